// Round 7
// baseline (630.353 us; speedup 1.0000x reference)
//
#include <hip/hip_runtime.h>
#include <hip/hip_fp16.h>

#define DD 128
#define KK 20
#define TRR 16

typedef unsigned int uint_t;
typedef unsigned short ushort_t;
typedef unsigned char uchar_t;
typedef _Float16 f16x8 __attribute__((ext_vector_type(8)));
typedef float f32x4 __attribute__((ext_vector_type(4)));
typedef float f32x2 __attribute__((ext_vector_type(2)));

union U16 { uint4 u4; __half2 h2[4]; };
union UH { __half h; ushort_t s; };

__device__ __forceinline__ float fast_tanh(float x) {
  const float e = __expf(2.f * x);
  return 1.f - 2.f / (e + 1.f);
}

// unpack 8 fp8 (uint2) -> accumulate into 8 f32
__device__ __forceinline__ void f8acc(float* a, const uint2 v) {
  f32x2 p;
  p = __builtin_amdgcn_cvt_pk_f32_fp8(v.x, false); a[0] += p[0]; a[1] += p[1];
  p = __builtin_amdgcn_cvt_pk_f32_fp8(v.x, true);  a[2] += p[0]; a[3] += p[1];
  p = __builtin_amdgcn_cvt_pk_f32_fp8(v.y, false); a[4] += p[0]; a[5] += p[1];
  p = __builtin_amdgcn_cvt_pk_f32_fp8(v.y, true);  a[6] += p[0]; a[7] += p[1];
}

__device__ __forceinline__ uint4 packh8(const float* a, float s) {
  UH h[8];
#pragma unroll
  for (int i = 0; i < 8; ++i) h[i].h = __float2half_rn(a[i] * s);
  uint4 o;
  o.x = (uint_t)h[0].s | ((uint_t)h[1].s << 16);
  o.y = (uint_t)h[2].s | ((uint_t)h[3].s << 16);
  o.z = (uint_t)h[4].s | ((uint_t)h[5].s << 16);
  o.w = (uint_t)h[6].s | ((uint_t)h[7].s << 16);
  return o;
}

// ---------------------------------------------------------------------------
// k_cvt3: three f32 tables -> contiguous fp16 region + contiguous fp8 region.
// ---------------------------------------------------------------------------
struct CvtArgs {
  const float* item; const float* loc; const float* timet;
  ushort_t* dst16; uchar_t* dst8;
};

__global__ __launch_bounds__(256)
void k_cvt3(CvtArgs a) {
  const int t = blockIdx.x * blockDim.x + threadIdx.x;  // 7000*256 = 1,792,000
  const float* src;
  if (t < 1600000) src = a.item + (size_t)t * 8;
  else if (t < 1760000) src = a.loc + ((size_t)t - 1600000) * 8;
  else src = a.timet + ((size_t)t - 1760000) * 8;
  const float4* ip = reinterpret_cast<const float4*>(src);
  const float4 x = ip[0], y = ip[1];
  UH h[8];
  h[0].h = __float2half_rn(x.x); h[1].h = __float2half_rn(x.y);
  h[2].h = __float2half_rn(x.z); h[3].h = __float2half_rn(x.w);
  h[4].h = __float2half_rn(y.x); h[5].h = __float2half_rn(y.y);
  h[6].h = __float2half_rn(y.z); h[7].h = __float2half_rn(y.w);
  uint4 o;
  o.x = (uint_t)h[0].s | ((uint_t)h[1].s << 16);
  o.y = (uint_t)h[2].s | ((uint_t)h[3].s << 16);
  o.z = (uint_t)h[4].s | ((uint_t)h[5].s << 16);
  o.w = (uint_t)h[6].s | ((uint_t)h[7].s << 16);
  reinterpret_cast<uint4*>(a.dst16)[t] = o;
  uint_t p0 = __builtin_amdgcn_cvt_pk_fp8_f32(x.x, x.y, 0u, false);
  p0 = __builtin_amdgcn_cvt_pk_fp8_f32(x.z, x.w, p0, true);
  uint_t p1 = __builtin_amdgcn_cvt_pk_fp8_f32(y.x, y.y, 0u, false);
  p1 = __builtin_amdgcn_cvt_pk_fp8_f32(y.z, y.w, p1, true);
  uint2 q; q.x = p0; q.y = p1;
  reinterpret_cast<uint2*>(a.dst8)[t] = q;
}

// ---------------------------------------------------------------------------
// k_pack10: all 10 weight matrices -> MFMA B-fragment order fp16.
// Fragment (kt,nt): lane l, reg j <- W[kt*32 + (l>>4)*8 + j][nt*16 + (l&15)]
// ---------------------------------------------------------------------------
struct PackArgs {
  const float* src[10];
  ushort_t* dst;
};

__global__ __launch_bounds__(256)
void k_pack10(PackArgs a) {
  const int b = blockIdx.x, tid = threadIdx.x;
  int job, tin;
  size_t doff;
  if (b < 112) {
    job = b >> 4; tin = ((b & 15) << 8) | tid;
    doff = (size_t)job * 32768;
  } else {
    job = 7 + ((b - 112) >> 3); tin = (((b - 112) & 7) << 8) | tid;
    doff = 7ull * 32768 + (size_t)(job - 7) * 16384;
  }
  const float* W = a.src[job];
  const int l = tin & 63;
  const int ktnt = tin >> 6;
  const int nt = ktnt & 7;
  const int kt = ktnt >> 3;
  const int col = nt * 16 + (l & 15);
  const int kb = kt * 32 + ((l >> 4) << 3);
  UH h[8];
#pragma unroll
  for (int j = 0; j < 8; ++j) h[j].h = __float2half_rn(W[(size_t)(kb + j) * DD + col]);
  uint4 o;
  o.x = (uint_t)h[0].s | ((uint_t)h[1].s << 16);
  o.y = (uint_t)h[2].s | ((uint_t)h[3].s << 16);
  o.z = (uint_t)h[4].s | ((uint_t)h[5].s << 16);
  o.w = (uint_t)h[6].s | ((uint_t)h[7].s << 16);
  *reinterpret_cast<uint4*>(a.dst + doff + (size_t)ktnt * 512 + l * 8) = o;
}

// ---------------------------------------------------------------------------
// k_mega: whole graph in one kernel. fp8 gather tables, fp16 self/MFMA path.
//  blocks 0..127: locs/times groups; 128..: items.
// ---------------------------------------------------------------------------
struct MegaArgs {
  // items
  const int* item_idx; const ushort_t* item_t;
  const int* nbI[3]; const uchar_t* embI[3]; const ushort_t* pWI[3]; const float* bI[3];
  const ushort_t* pWsI; const float* bsI; const float* qI;
  ushort_t* hI; float* wsumI;
  // locs (g=0) / times (g=1)
  const int* sidx[2]; const ushort_t* st[2];
  const int* nbS[2][2]; const uchar_t* embS[2][2];
  const ushort_t* pWS[2][2]; const float* bS[2][2];
  const ushort_t* pWsS[2]; const float* bsS[2]; const float* qS[2];
  const float* session;
  ushort_t* hS[2]; float* wsumS[2];
};

__global__ __launch_bounds__(256, 7)
void k_mega(MegaArgs a) {
  __shared__ int ids[TRR];
  __shared__ int nidx[3][TRR][KK];
  __shared__ __align__(16) ushort_t xs[TRR][4 * DD + 8];   // 520: self|s1|s2|s3
  __shared__ float red[4][TRR];

  const int tid = threadIdx.x;
  const int l = tid & 63;
  const int w = tid >> 6;
  const int bid = blockIdx.x;

  const bool isS = bid < 128;
  const int g = isS ? (bid >> 6) : 0;
  const int bl = isS ? (bid & 63) : (bid - 128);
  const int n0 = bl * TRR;

  const int* sidx;
  const ushort_t* selft;
  const int* nb_[3];
  const uchar_t* emb_[3];
  const ushort_t* pW_[3];
  const float* bias_[3];
  const ushort_t* pws; const float* bss; const float* qp;
  ushort_t* hd; float* wbase;
  if (!isS) {
    sidx = a.item_idx; selft = a.item_t;
    nb_[0] = a.nbI[0]; nb_[1] = a.nbI[1]; nb_[2] = a.nbI[2];
    emb_[0] = a.embI[0]; emb_[1] = a.embI[1]; emb_[2] = a.embI[2];
    pW_[0] = a.pWI[0]; pW_[1] = a.pWI[1]; pW_[2] = a.pWI[2];
    bias_[0] = a.bI[0]; bias_[1] = a.bI[1]; bias_[2] = a.bI[2];
    pws = a.pWsI; bss = a.bsI; qp = a.qI;
    hd = a.hI; wbase = a.wsumI;
  } else if (g == 0) {
    sidx = a.sidx[0]; selft = a.st[0];
    nb_[0] = a.nbS[0][0]; nb_[1] = a.nbS[0][1]; nb_[2] = nullptr;
    emb_[0] = a.embS[0][0]; emb_[1] = a.embS[0][1]; emb_[2] = nullptr;
    pW_[0] = a.pWS[0][0]; pW_[1] = a.pWS[0][1]; pW_[2] = nullptr;
    bias_[0] = a.bS[0][0]; bias_[1] = a.bS[0][1]; bias_[2] = nullptr;
    pws = a.pWsS[0]; bss = a.bsS[0]; qp = a.qS[0];
    hd = a.hS[0]; wbase = a.wsumS[0];
  } else {
    sidx = a.sidx[1]; selft = a.st[1];
    nb_[0] = a.nbS[1][0]; nb_[1] = a.nbS[1][1]; nb_[2] = nullptr;
    emb_[0] = a.embS[1][0]; emb_[1] = a.embS[1][1]; emb_[2] = nullptr;
    pW_[0] = a.pWS[1][0]; pW_[1] = a.pWS[1][1]; pW_[2] = nullptr;
    bias_[0] = a.bS[1][0]; bias_[1] = a.bS[1][1]; bias_[2] = nullptr;
    pws = a.pWsS[1]; bss = a.bsS[1]; qp = a.qS[1];
    hd = a.hS[1]; wbase = a.wsumS[1];
  }

  if (tid < TRR) ids[tid] = sidx[n0 + tid];
  __syncthreads();

  const int gr = tid >> 4;        // row 0..15
  const int gsl = tid & 15;       // 8-elem slice within a row

  // stage neighbor index lists
#pragma unroll
  for (int e = 0; e < 3; ++e) {
    if (nb_[e]) {
      for (int t = tid; t < TRR * KK; t += 256) {
        const int rr = t / KK, kk = t - rr * KK;
        nidx[e][rr][kk] = nb_[e][(size_t)ids[rr] * KK + kk];
      }
    }
  }
  // self half of x (fp16 table)
  *reinterpret_cast<uint4*>(&xs[gr][gsl * 8]) =
      *reinterpret_cast<const uint4*>(selft + ((size_t)ids[gr] << 7) + gsl * 8);
  __syncthreads();

  // ---- concurrent fp8 gathers for all edges, f32 mean accumulation ----
  if (!isS) {
    float a0[8], a1[8], a2[8];
#pragma unroll
    for (int i = 0; i < 8; ++i) { a0[i] = 0.f; a1[i] = 0.f; a2[i] = 0.f; }
#pragma unroll
    for (int kb = 0; kb < KK; kb += 4) {
      uint2 u0[4], u1[4], u2[4];
#pragma unroll
      for (int j = 0; j < 4; ++j)
        u0[j] = *reinterpret_cast<const uint2*>(emb_[0] + ((size_t)nidx[0][gr][kb + j] << 7) + gsl * 8);
#pragma unroll
      for (int j = 0; j < 4; ++j)
        u1[j] = *reinterpret_cast<const uint2*>(emb_[1] + ((size_t)nidx[1][gr][kb + j] << 7) + gsl * 8);
#pragma unroll
      for (int j = 0; j < 4; ++j)
        u2[j] = *reinterpret_cast<const uint2*>(emb_[2] + ((size_t)nidx[2][gr][kb + j] << 7) + gsl * 8);
#pragma unroll
      for (int j = 0; j < 4; ++j) {
        f8acc(a0, u0[j]); f8acc(a1, u1[j]); f8acc(a2, u2[j]);
      }
    }
    const float sc = 1.f / KK;
    *reinterpret_cast<uint4*>(&xs[gr][1 * DD + gsl * 8]) = packh8(a0, sc);
    *reinterpret_cast<uint4*>(&xs[gr][2 * DD + gsl * 8]) = packh8(a1, sc);
    *reinterpret_cast<uint4*>(&xs[gr][3 * DD + gsl * 8]) = packh8(a2, sc);
  } else {
    float a0[8], a1[8];
#pragma unroll
    for (int i = 0; i < 8; ++i) { a0[i] = 0.f; a1[i] = 0.f; }
#pragma unroll
    for (int kb = 0; kb < KK; kb += 5) {
      uint2 u0[5], u1[5];
#pragma unroll
      for (int j = 0; j < 5; ++j)
        u0[j] = *reinterpret_cast<const uint2*>(emb_[0] + ((size_t)nidx[0][gr][kb + j] << 7) + gsl * 8);
#pragma unroll
      for (int j = 0; j < 5; ++j)
        u1[j] = *reinterpret_cast<const uint2*>(emb_[1] + ((size_t)nidx[1][gr][kb + j] << 7) + gsl * 8);
#pragma unroll
      for (int j = 0; j < 5; ++j) { f8acc(a0, u0[j]); f8acc(a1, u1[j]); }
    }
    const float sc = 1.f / KK;
    *reinterpret_cast<uint4*>(&xs[gr][1 * DD + gsl * 8]) = packh8(a0, sc);
    *reinterpret_cast<uint4*>(&xs[gr][2 * DD + gsl * 8]) = packh8(a1, sc);
    // session -> slot 3 (fp16) + hbuf m=2
    const float* srow = a.session + (size_t)(n0 + gr) * DD + gsl * 8;
    const float4 v0 = *reinterpret_cast<const float4*>(srow);
    const float4 v1 = *reinterpret_cast<const float4*>(srow + 4);
    float sv[8] = {v0.x, v0.y, v0.z, v0.w, v1.x, v1.y, v1.z, v1.w};
    const uint4 o = packh8(sv, 1.f);
    *reinterpret_cast<uint4*>(&xs[gr][3 * DD + gsl * 8]) = o;
    *reinterpret_cast<uint4*>(hd + (size_t)(n0 + gr) * 3 * DD + 2 * DD + gsl * 8) = o;
  }
  __syncthreads();

  // ---- per-edge MFMA + score ----
  const int nt0 = 2 * w;
  const int lcol = l & 15;
  const int g8 = (l >> 4) << 3;
  const int col0 = nt0 * 16 + lcol;
  const int col1 = col0 + 16;

#pragma unroll
  for (int e = 0; e < 3; ++e) {
    const bool full = (!isS) || (e < 2);
    if (full) {
      const ushort_t* pWp = pW_[e];
      const float* bp = bias_[e];
      f32x4 acc0, acc1;
      {
        const float b0 = bp[col0], b1 = bp[col1];
        acc0 = (f32x4){b0, b0, b0, b0};
        acc1 = (f32x4){b1, b1, b1, b1};
#pragma unroll
        for (int kt = 0; kt < 8; ++kt) {
          const int xcol = (kt < 4) ? (kt * 32 + g8) : (e * DD + kt * 32 + g8);
          const f16x8 A = *reinterpret_cast<const f16x8*>((const void*)&xs[lcol][xcol]);
          const f16x8 B0 = *reinterpret_cast<const f16x8*>(
              (const void*)(pWp + ((size_t)(kt * 8 + nt0) * 512) + l * 8));
          const f16x8 B1 = *reinterpret_cast<const f16x8*>(
              (const void*)(pWp + ((size_t)(kt * 8 + nt0 + 1) * 512) + l * 8));
          acc0 = __builtin_amdgcn_mfma_f32_16x16x32_f16(A, B0, acc0, 0, 0, 0);
          acc1 = __builtin_amdgcn_mfma_f32_16x16x32_f16(A, B1, acc1, 0, 0, 0);
        }
#pragma unroll
        for (int j = 0; j < 4; ++j) {
          acc0[j] = fmaxf(acc0[j], 0.f);
          acc1[j] = fmaxf(acc1[j], 0.f);
        }
      }
      __syncthreads();  // all A-reads of slot e+1 done before overwrite
      {
        const int rbase = (l >> 4) << 2;
#pragma unroll
        for (int j = 0; j < 4; ++j) {
          const int row = rbase + j;
          UH h0, h1;
          h0.h = __float2half_rn(acc0[j]);
          h1.h = __float2half_rn(acc1[j]);
          hd[(size_t)(n0 + row) * 3 * DD + e * DD + col0] = h0.s;
          hd[(size_t)(n0 + row) * 3 * DD + e * DD + col1] = h1.s;
          xs[row][(e + 1) * DD + col0] = h0.s;
          xs[row][(e + 1) * DD + col1] = h1.s;
        }
      }
      __syncthreads();  // h visible in LDS
    }
    // score: t = h @ Ws + bs; w = sum_cols tanh(t)*q
    {
      const float b0 = bss[col0], b1 = bss[col1];
      f32x4 s0 = (f32x4){b0, b0, b0, b0};
      f32x4 s1 = (f32x4){b1, b1, b1, b1};
#pragma unroll
      for (int kt = 0; kt < 4; ++kt) {
        const f16x8 A = *reinterpret_cast<const f16x8*>(
            (const void*)&xs[lcol][(e + 1) * DD + kt * 32 + g8]);
        const f16x8 B0 = *reinterpret_cast<const f16x8*>(
            (const void*)(pws + ((size_t)(kt * 8 + nt0) * 512) + l * 8));
        const f16x8 B1 = *reinterpret_cast<const f16x8*>(
            (const void*)(pws + ((size_t)(kt * 8 + nt0 + 1) * 512) + l * 8));
        s0 = __builtin_amdgcn_mfma_f32_16x16x32_f16(A, B0, s0, 0, 0, 0);
        s1 = __builtin_amdgcn_mfma_f32_16x16x32_f16(A, B1, s1, 0, 0, 0);
      }
      const float q0 = qp[col0], q1 = qp[col1];
      float p[4];
#pragma unroll
      for (int j = 0; j < 4; ++j)
        p[j] = fast_tanh(s0[j]) * q0 + fast_tanh(s1[j]) * q1;
#pragma unroll
      for (int off = 1; off < 16; off <<= 1) {
#pragma unroll
        for (int j = 0; j < 4; ++j) p[j] += __shfl_xor(p[j], off, 64);
      }
      if (lcol == 0) {
        const int rbase = (l >> 4) << 2;
#pragma unroll
        for (int j = 0; j < 4; ++j) red[w][rbase + j] = p[j];
      }
    }
    __syncthreads();
    if (tid < TRR) {
      float s = red[0][tid] + red[1][tid] + red[2][tid] + red[3][tid];
#pragma unroll
      for (int off = 1; off < 16; off <<= 1) s += __shfl_xor(s, off, 64);
      if (tid == 0) atomicAdd(&wbase[(bl & 63) * 4 + e], s);
    }
    __syncthreads();
  }
}

// ---------------------------------------------------------------------------
__global__ void k_beta(const float* __restrict__ wsum, float* __restrict__ beta) {
  if (threadIdx.x == 0 && blockIdx.x == 0) {
    const float invN[3] = {1.f / 51200.f, 1.f / 1024.f, 1.f / 1024.f};
    for (int g = 0; g < 3; ++g) {
      float s0 = 0.f, s1 = 0.f, s2 = 0.f;
      for (int bkt = 0; bkt < 64; ++bkt) {
        s0 += wsum[g * 256 + bkt * 4 + 0];
        s1 += wsum[g * 256 + bkt * 4 + 1];
        s2 += wsum[g * 256 + bkt * 4 + 2];
      }
      s0 *= invN[g]; s1 *= invN[g]; s2 *= invN[g];
      const float mx = fmaxf(s0, fmaxf(s1, s2));
      const float e0 = expf(s0 - mx), e1 = expf(s1 - mx), e2 = expf(s2 - mx);
      const float inv = 1.f / (e0 + e1 + e2);
      beta[g * 4 + 0] = e0 * inv;
      beta[g * 4 + 1] = e1 * inv;
      beta[g * 4 + 2] = e2 * inv;
    }
  }
}

__global__ void k_out(const ushort_t* __restrict__ h, const float* __restrict__ beta,
                      float* __restrict__ out) {
  const int idx = blockIdx.x * blockDim.x + threadIdx.x;
  const int row = idx >> 7;
  const int g = (row < 51200) ? 0 : ((row < 52224) ? 1 : 2);
  const float* bt = beta + g * 4;
  const size_t base = (size_t)idx + (size_t)row * 2 * DD;
  UH a, b, c;
  a.s = h[base]; b.s = h[base + DD]; c.s = h[base + 2 * DD];
  out[idx] = bt[0] * __half2float(a.h) + bt[1] * __half2float(b.h) +
             bt[2] * __half2float(c.h);
}

// ---------------------------------------------------------------------------

extern "C" void kernel_launch(void* const* d_in, const int* in_sizes, int n_in,
                              void* d_out, int out_size, void* d_ws, size_t ws_size,
                              hipStream_t stream) {
  const int*   item     = (const int*)  d_in[0];
  const int*   locs     = (const int*)  d_in[1];
  const int*   times    = (const int*)  d_in[2];
  const float* session  = (const float*)d_in[3];
  const float* loc_emb  = (const float*)d_in[4];
  const float* time_emb = (const float*)d_in[5];
  const float* item_emb = (const float*)d_in[6];
  const int* nb_IL = (const int*)d_in[7];
  const int* nb_TL = (const int*)d_in[8];
  const int* nb_IT = (const int*)d_in[9];
  const int* nb_LT = (const int*)d_in[10];
  const int* nb_II = (const int*)d_in[11];
  const int* nb_LI = (const int*)d_in[12];
  const int* nb_TI = (const int*)d_in[13];
  const float* W_IL = (const float*)d_in[14]; const float* b_IL = (const float*)d_in[15];
  const float* W_TL = (const float*)d_in[16]; const float* b_TL = (const float*)d_in[17];
  const float* W_IT = (const float*)d_in[18]; const float* b_IT = (const float*)d_in[19];
  const float* W_LT = (const float*)d_in[20]; const float* b_LT = (const float*)d_in[21];
  const float* W_II = (const float*)d_in[22]; const float* b_II = (const float*)d_in[23];
  const float* W_LI = (const float*)d_in[24]; const float* b_LI = (const float*)d_in[25];
  const float* W_TI = (const float*)d_in[26]; const float* b_TI = (const float*)d_in[27];
  const float* Ws_l = (const float*)d_in[28]; const float* bs_l = (const float*)d_in[29];
  const float* q_l  = (const float*)d_in[30];
  const float* Ws_t = (const float*)d_in[31]; const float* bs_t = (const float*)d_in[32];
  const float* q_t  = (const float*)d_in[33];
  const float* Ws_i = (const float*)d_in[34]; const float* bs_i = (const float*)d_in[35];
  const float* q_i  = (const float*)d_in[36];

  float* outp = (float*)d_out;

  // ws: wsum/beta(16K) | packed W(544K) | hbuf fp16(40.9M) | fp16 tables(28.7M)
  //     | fp8 tables(14.3M)  -- total ~84.5MB (ws >= 110MB established R2)
  char* wsb = (char*)d_ws;
  float* wsum  = (float*)wsb;
  float* betap = (float*)wsb + 1024;
  ushort_t* pk = (ushort_t*)(wsb + 16384);
  ushort_t* pk_II = pk;
  ushort_t* pk_TI = pk_II + 32768;
  ushort_t* pk_LI = pk_TI + 32768;
  ushort_t* pk_IL = pk_LI + 32768;
  ushort_t* pk_TL = pk_IL + 32768;
  ushort_t* pk_IT = pk_TL + 32768;
  ushort_t* pk_LT = pk_IT + 32768;
  ushort_t* pk_Wi = pk_LT + 32768;
  ushort_t* pk_Wl = pk_Wi + 16384;
  ushort_t* pk_Wt = pk_Wl + 16384;
  ushort_t* hbuf  = pk_Wt + 16384;
  ushort_t* item_h = hbuf + (size_t)53248 * 3 * DD;
  ushort_t* loc_h  = item_h + (size_t)100000 * DD;
  ushort_t* time_h = loc_h + (size_t)10000 * DD;
  uchar_t* item_8 = (uchar_t*)(time_h + (size_t)2000 * DD);
  uchar_t* loc_8  = item_8 + (size_t)100000 * DD;
  uchar_t* time_8 = loc_8 + (size_t)10000 * DD;

  hipMemsetAsync(d_ws, 0, 16384, stream);

  CvtArgs ca;
  ca.item = item_emb; ca.loc = loc_emb; ca.timet = time_emb;
  ca.dst16 = item_h; ca.dst8 = item_8;
  k_cvt3<<<dim3(7000), dim3(256), 0, stream>>>(ca);

  PackArgs pa;
  pa.src[0] = W_II; pa.src[1] = W_TI; pa.src[2] = W_LI;
  pa.src[3] = W_IL; pa.src[4] = W_TL; pa.src[5] = W_IT; pa.src[6] = W_LT;
  pa.src[7] = Ws_i; pa.src[8] = Ws_l; pa.src[9] = Ws_t;
  pa.dst = pk;
  k_pack10<<<dim3(136), dim3(256), 0, stream>>>(pa);

  ushort_t* h_items = hbuf;
  ushort_t* h_locs  = hbuf + (size_t)51200 * 3 * DD;
  ushort_t* h_times = hbuf + (size_t)52224 * 3 * DD;

  MegaArgs ma;
  ma.item_idx = item; ma.item_t = item_h;
  ma.nbI[0] = nb_II; ma.nbI[1] = nb_TI; ma.nbI[2] = nb_LI;
  ma.embI[0] = item_8; ma.embI[1] = time_8; ma.embI[2] = loc_8;
  ma.pWI[0] = pk_II; ma.pWI[1] = pk_TI; ma.pWI[2] = pk_LI;
  ma.bI[0] = b_II; ma.bI[1] = b_TI; ma.bI[2] = b_LI;
  ma.pWsI = pk_Wi; ma.bsI = bs_i; ma.qI = q_i;
  ma.hI = h_items; ma.wsumI = wsum + 0;
  ma.sidx[0] = locs;  ma.sidx[1] = times;
  ma.st[0] = loc_h;   ma.st[1] = time_h;
  ma.nbS[0][0] = nb_IL; ma.nbS[0][1] = nb_TL;
  ma.nbS[1][0] = nb_IT; ma.nbS[1][1] = nb_LT;
  ma.embS[0][0] = item_8; ma.embS[0][1] = time_8;
  ma.embS[1][0] = item_8; ma.embS[1][1] = loc_8;
  ma.pWS[0][0] = pk_IL; ma.pWS[0][1] = pk_TL;
  ma.pWS[1][0] = pk_IT; ma.pWS[1][1] = pk_LT;
  ma.bS[0][0] = b_IL; ma.bS[0][1] = b_TL;
  ma.bS[1][0] = b_IT; ma.bS[1][1] = b_LT;
  ma.pWsS[0] = pk_Wl; ma.pWsS[1] = pk_Wt;
  ma.bsS[0] = bs_l; ma.bsS[1] = bs_t;
  ma.qS[0] = q_l; ma.qS[1] = q_t;
  ma.session = session;
  ma.hS[0] = h_locs; ma.hS[1] = h_times;
  ma.wsumS[0] = wsum + 256; ma.wsumS[1] = wsum + 512;
  k_mega<<<dim3(128 + 51200 / TRR), dim3(256), 0, stream>>>(ma);

  k_beta<<<dim3(1), dim3(64), 0, stream>>>(wsum, betap);
  k_out<<<dim3((53248 * 128) / 256), dim3(256), 0, stream>>>(hbuf, betap, outp);
}

// Round 8
// 145.367 us; speedup vs baseline: 4.3363x; 4.3363x over previous
//
#include <hip/hip_runtime.h>
#include <hip/hip_fp16.h>

#define DD 128
#define KK 20
#define TRR 16

typedef unsigned int uint_t;
typedef unsigned short ushort_t;
typedef _Float16 f16x8 __attribute__((ext_vector_type(8)));
typedef float f32x4 __attribute__((ext_vector_type(4)));

union U16 { uint4 u4; __half2 h2[4]; };
union UH { __half h; ushort_t s; };

__device__ __forceinline__ float fast_tanh(float x) {
  const float e = __expf(2.f * x);
  return 1.f - 2.f / (e + 1.f);
}

__device__ __forceinline__ void acc_add(U16& a, const uint4 v) {
  U16 u; u.u4 = v;
  a.h2[0] = __hadd2(a.h2[0], u.h2[0]);
  a.h2[1] = __hadd2(a.h2[1], u.h2[1]);
  a.h2[2] = __hadd2(a.h2[2], u.h2[2]);
  a.h2[3] = __hadd2(a.h2[3], u.h2[3]);
}

// ---------------------------------------------------------------------------
// k_cvt3: all three f32 tables -> contiguous fp16 region. 8 elems/thread.
// ---------------------------------------------------------------------------
struct CvtArgs {
  const float* item; const float* loc; const float* timet;
  ushort_t* dst;
};

__global__ __launch_bounds__(256)
void k_cvt3(CvtArgs a) {
  const int t = blockIdx.x * blockDim.x + threadIdx.x;  // 7000*256 = 1,792,000
  const float* src;
  if (t < 1600000) src = a.item + (size_t)t * 8;
  else if (t < 1760000) src = a.loc + ((size_t)t - 1600000) * 8;
  else src = a.timet + ((size_t)t - 1760000) * 8;
  const float4* ip = reinterpret_cast<const float4*>(src);
  const float4 x = ip[0], y = ip[1];
  UH h[8];
  h[0].h = __float2half_rn(x.x); h[1].h = __float2half_rn(x.y);
  h[2].h = __float2half_rn(x.z); h[3].h = __float2half_rn(x.w);
  h[4].h = __float2half_rn(y.x); h[5].h = __float2half_rn(y.y);
  h[6].h = __float2half_rn(y.z); h[7].h = __float2half_rn(y.w);
  uint4 o;
  o.x = (uint_t)h[0].s | ((uint_t)h[1].s << 16);
  o.y = (uint_t)h[2].s | ((uint_t)h[3].s << 16);
  o.z = (uint_t)h[4].s | ((uint_t)h[5].s << 16);
  o.w = (uint_t)h[6].s | ((uint_t)h[7].s << 16);
  reinterpret_cast<uint4*>(a.dst)[t] = o;
}

// ---------------------------------------------------------------------------
// k_pack10: all 10 weight matrices -> MFMA B-fragment order fp16.
// Fragment (kt,nt): lane l, reg j <- W[kt*32 + (l>>4)*8 + j][nt*16 + (l&15)]
// ---------------------------------------------------------------------------
struct PackArgs {
  const float* src[10];
  ushort_t* dst;
};

__global__ __launch_bounds__(256)
void k_pack10(PackArgs a) {
  const int b = blockIdx.x, tid = threadIdx.x;
  int job, tin;
  size_t doff;
  if (b < 112) {
    job = b >> 4; tin = ((b & 15) << 8) | tid;
    doff = (size_t)job * 32768;
  } else {
    job = 7 + ((b - 112) >> 3); tin = (((b - 112) & 7) << 8) | tid;
    doff = 7ull * 32768 + (size_t)(job - 7) * 16384;
  }
  const float* W = a.src[job];
  const int l = tin & 63;
  const int ktnt = tin >> 6;
  const int nt = ktnt & 7;
  const int kt = ktnt >> 3;
  const int col = nt * 16 + (l & 15);
  const int kb = kt * 32 + ((l >> 4) << 3);
  UH h[8];
#pragma unroll
  for (int j = 0; j < 8; ++j) h[j].h = __float2half_rn(W[(size_t)(kb + j) * DD + col]);
  uint4 o;
  o.x = (uint_t)h[0].s | ((uint_t)h[1].s << 16);
  o.y = (uint_t)h[2].s | ((uint_t)h[3].s << 16);
  o.z = (uint_t)h[4].s | ((uint_t)h[5].s << 16);
  o.w = (uint_t)h[6].s | ((uint_t)h[7].s << 16);
  *reinterpret_cast<uint4*>(a.dst + doff + (size_t)ktnt * 512 + l * 8) = o;
}

// ---------------------------------------------------------------------------
// k_mega: whole graph in one kernel, fp16 tables.
//  blocks 0..127: locs/times groups; 128..: items.
//  __launch_bounds__(256,7): 7 blocks/CU (LDS-limited), VGPR cap ~73 — the
//  fp16 gather path needs ~48 regs so no spill (R7 lesson: fp8's f32
//  accumulators blew this cap and went to scratch, 6x regression).
// ---------------------------------------------------------------------------
struct MegaArgs {
  // items
  const int* item_idx; const ushort_t* item_t;
  const int* nbI[3]; const ushort_t* embI[3]; const ushort_t* pWI[3]; const float* bI[3];
  const ushort_t* pWsI; const float* bsI; const float* qI;
  ushort_t* hI; float* wsumI;
  // locs (g=0) / times (g=1)
  const int* sidx[2]; const ushort_t* st[2];
  const int* nbS[2][2]; const ushort_t* embS[2][2];
  const ushort_t* pWS[2][2]; const float* bS[2][2];
  const ushort_t* pWsS[2]; const float* bsS[2]; const float* qS[2];
  const float* session;
  ushort_t* hS[2]; float* wsumS[2];
};

__global__ __launch_bounds__(256, 7)
void k_mega(MegaArgs a) {
  __shared__ int ids[TRR];
  __shared__ int nidx[3][TRR][KK];
  __shared__ __align__(16) ushort_t xs[TRR][4 * DD + 8];   // 520: self|s1|s2|s3
  __shared__ float red[4][TRR];

  const int tid = threadIdx.x;
  const int l = tid & 63;
  const int w = tid >> 6;
  const int bid = blockIdx.x;

  const bool isS = bid < 128;
  const int g = isS ? (bid >> 6) : 0;
  const int bl = isS ? (bid & 63) : (bid - 128);
  const int n0 = bl * TRR;

  const int* sidx;
  const ushort_t* selft;
  const int* nb_[3];
  const ushort_t* emb_[3];
  const ushort_t* pW_[3];
  const float* bias_[3];
  const ushort_t* pws; const float* bss; const float* qp;
  ushort_t* hd; float* wbase;
  if (!isS) {
    sidx = a.item_idx; selft = a.item_t;
    nb_[0] = a.nbI[0]; nb_[1] = a.nbI[1]; nb_[2] = a.nbI[2];
    emb_[0] = a.embI[0]; emb_[1] = a.embI[1]; emb_[2] = a.embI[2];
    pW_[0] = a.pWI[0]; pW_[1] = a.pWI[1]; pW_[2] = a.pWI[2];
    bias_[0] = a.bI[0]; bias_[1] = a.bI[1]; bias_[2] = a.bI[2];
    pws = a.pWsI; bss = a.bsI; qp = a.qI;
    hd = a.hI; wbase = a.wsumI;
  } else if (g == 0) {
    sidx = a.sidx[0]; selft = a.st[0];
    nb_[0] = a.nbS[0][0]; nb_[1] = a.nbS[0][1]; nb_[2] = nullptr;
    emb_[0] = a.embS[0][0]; emb_[1] = a.embS[0][1]; emb_[2] = nullptr;
    pW_[0] = a.pWS[0][0]; pW_[1] = a.pWS[0][1]; pW_[2] = nullptr;
    bias_[0] = a.bS[0][0]; bias_[1] = a.bS[0][1]; bias_[2] = nullptr;
    pws = a.pWsS[0]; bss = a.bsS[0]; qp = a.qS[0];
    hd = a.hS[0]; wbase = a.wsumS[0];
  } else {
    sidx = a.sidx[1]; selft = a.st[1];
    nb_[0] = a.nbS[1][0]; nb_[1] = a.nbS[1][1]; nb_[2] = nullptr;
    emb_[0] = a.embS[1][0]; emb_[1] = a.embS[1][1]; emb_[2] = nullptr;
    pW_[0] = a.pWS[1][0]; pW_[1] = a.pWS[1][1]; pW_[2] = nullptr;
    bias_[0] = a.bS[1][0]; bias_[1] = a.bS[1][1]; bias_[2] = nullptr;
    pws = a.pWsS[1]; bss = a.bsS[1]; qp = a.qS[1];
    hd = a.hS[1]; wbase = a.wsumS[1];
  }

  if (tid < TRR) ids[tid] = sidx[n0 + tid];
  __syncthreads();

  const int gr = tid >> 4;        // row 0..15
  const int gsl = tid & 15;       // 16B slice within a row

  // stage neighbor index lists (edge-major)
#pragma unroll
  for (int e = 0; e < 3; ++e) {
    if (nb_[e]) {
      for (int t = tid; t < TRR * KK; t += 256) {
        const int rr = t / KK, kk = t - rr * KK;
        nidx[e][rr][kk] = nb_[e][(size_t)ids[rr] * KK + kk];
      }
    }
  }
  // self half of x
  *reinterpret_cast<uint4*>(&xs[gr][gsl * 8]) =
      *reinterpret_cast<const uint4*>(selft + ((size_t)ids[gr] << 7) + gsl * 8);
  __syncthreads();

  // ---- concurrent gathers for all edges ----
  const __half2 sc = __float2half2_rn(1.f / KK);
  const __half2 z = __float2half2_rn(0.f);
  if (!isS) {
    U16 acc0, acc1, acc2;
    acc0.h2[0] = z; acc0.h2[1] = z; acc0.h2[2] = z; acc0.h2[3] = z;
    acc1 = acc0; acc2 = acc0;
#pragma unroll
    for (int kb = 0; kb < KK; kb += 4) {
      uint4 u0[4], u1[4], u2[4];
#pragma unroll
      for (int j = 0; j < 4; ++j)
        u0[j] = *reinterpret_cast<const uint4*>(emb_[0] + ((size_t)nidx[0][gr][kb + j] << 7) + gsl * 8);
#pragma unroll
      for (int j = 0; j < 4; ++j)
        u1[j] = *reinterpret_cast<const uint4*>(emb_[1] + ((size_t)nidx[1][gr][kb + j] << 7) + gsl * 8);
#pragma unroll
      for (int j = 0; j < 4; ++j)
        u2[j] = *reinterpret_cast<const uint4*>(emb_[2] + ((size_t)nidx[2][gr][kb + j] << 7) + gsl * 8);
#pragma unroll
      for (int j = 0; j < 4; ++j) {
        acc_add(acc0, u0[j]);
        acc_add(acc1, u1[j]);
        acc_add(acc2, u2[j]);
      }
    }
#pragma unroll
    for (int i = 0; i < 4; ++i) {
      acc0.h2[i] = __hmul2(acc0.h2[i], sc);
      acc1.h2[i] = __hmul2(acc1.h2[i], sc);
      acc2.h2[i] = __hmul2(acc2.h2[i], sc);
    }
    *reinterpret_cast<uint4*>(&xs[gr][1 * DD + gsl * 8]) = acc0.u4;
    *reinterpret_cast<uint4*>(&xs[gr][2 * DD + gsl * 8]) = acc1.u4;
    *reinterpret_cast<uint4*>(&xs[gr][3 * DD + gsl * 8]) = acc2.u4;
  } else {
    U16 acc0, acc1;
    acc0.h2[0] = z; acc0.h2[1] = z; acc0.h2[2] = z; acc0.h2[3] = z;
    acc1 = acc0;
#pragma unroll
    for (int kb = 0; kb < KK; kb += 5) {
      uint4 u0[5], u1[5];
#pragma unroll
      for (int j = 0; j < 5; ++j)
        u0[j] = *reinterpret_cast<const uint4*>(emb_[0] + ((size_t)nidx[0][gr][kb + j] << 7) + gsl * 8);
#pragma unroll
      for (int j = 0; j < 5; ++j)
        u1[j] = *reinterpret_cast<const uint4*>(emb_[1] + ((size_t)nidx[1][gr][kb + j] << 7) + gsl * 8);
#pragma unroll
      for (int j = 0; j < 5; ++j) {
        acc_add(acc0, u0[j]);
        acc_add(acc1, u1[j]);
      }
    }
#pragma unroll
    for (int i = 0; i < 4; ++i) {
      acc0.h2[i] = __hmul2(acc0.h2[i], sc);
      acc1.h2[i] = __hmul2(acc1.h2[i], sc);
    }
    *reinterpret_cast<uint4*>(&xs[gr][1 * DD + gsl * 8]) = acc0.u4;
    *reinterpret_cast<uint4*>(&xs[gr][2 * DD + gsl * 8]) = acc1.u4;
    // session -> slot 3 (fp16) + hbuf m=2
    const float* srow = a.session + (size_t)(n0 + gr) * DD + gsl * 8;
    const float4 v0 = *reinterpret_cast<const float4*>(srow);
    const float4 v1 = *reinterpret_cast<const float4*>(srow + 4);
    UH h0, h1, h2, h3, h4, h5, h6, h7;
    h0.h = __float2half_rn(v0.x); h1.h = __float2half_rn(v0.y);
    h2.h = __float2half_rn(v0.z); h3.h = __float2half_rn(v0.w);
    h4.h = __float2half_rn(v1.x); h5.h = __float2half_rn(v1.y);
    h6.h = __float2half_rn(v1.z); h7.h = __float2half_rn(v1.w);
    uint4 o;
    o.x = (uint_t)h0.s | ((uint_t)h1.s << 16);
    o.y = (uint_t)h2.s | ((uint_t)h3.s << 16);
    o.z = (uint_t)h4.s | ((uint_t)h5.s << 16);
    o.w = (uint_t)h6.s | ((uint_t)h7.s << 16);
    *reinterpret_cast<uint4*>(&xs[gr][3 * DD + gsl * 8]) = o;
    *reinterpret_cast<uint4*>(hd + (size_t)(n0 + gr) * 3 * DD + 2 * DD + gsl * 8) = o;
  }
  __syncthreads();

  // ---- per-edge MFMA + score ----
  const int nt0 = 2 * w;
  const int lcol = l & 15;
  const int g8 = (l >> 4) << 3;
  const int col0 = nt0 * 16 + lcol;
  const int col1 = col0 + 16;

#pragma unroll
  for (int e = 0; e < 3; ++e) {
    const bool full = (!isS) || (e < 2);
    if (full) {
      const ushort_t* pWp = pW_[e];
      const float* bp = bias_[e];
      f32x4 acc0, acc1;
      {
        const float b0 = bp[col0], b1 = bp[col1];
        acc0 = (f32x4){b0, b0, b0, b0};
        acc1 = (f32x4){b1, b1, b1, b1};
#pragma unroll
        for (int kt = 0; kt < 8; ++kt) {
          const int xcol = (kt < 4) ? (kt * 32 + g8) : (e * DD + kt * 32 + g8);
          const f16x8 A = *reinterpret_cast<const f16x8*>((const void*)&xs[lcol][xcol]);
          const f16x8 B0 = *reinterpret_cast<const f16x8*>(
              (const void*)(pWp + ((size_t)(kt * 8 + nt0) * 512) + l * 8));
          const f16x8 B1 = *reinterpret_cast<const f16x8*>(
              (const void*)(pWp + ((size_t)(kt * 8 + nt0 + 1) * 512) + l * 8));
          acc0 = __builtin_amdgcn_mfma_f32_16x16x32_f16(A, B0, acc0, 0, 0, 0);
          acc1 = __builtin_amdgcn_mfma_f32_16x16x32_f16(A, B1, acc1, 0, 0, 0);
        }
#pragma unroll
        for (int j = 0; j < 4; ++j) {
          acc0[j] = fmaxf(acc0[j], 0.f);
          acc1[j] = fmaxf(acc1[j], 0.f);
        }
      }
      __syncthreads();  // all A-reads of slot e+1 done before overwrite
      {
        const int rbase = (l >> 4) << 2;
#pragma unroll
        for (int j = 0; j < 4; ++j) {
          const int row = rbase + j;
          UH h0, h1;
          h0.h = __float2half_rn(acc0[j]);
          h1.h = __float2half_rn(acc1[j]);
          hd[(size_t)(n0 + row) * 3 * DD + e * DD + col0] = h0.s;
          hd[(size_t)(n0 + row) * 3 * DD + e * DD + col1] = h1.s;
          xs[row][(e + 1) * DD + col0] = h0.s;
          xs[row][(e + 1) * DD + col1] = h1.s;
        }
      }
      __syncthreads();  // h visible in LDS
    }
    // score: t = h @ Ws + bs; w = sum_cols tanh(t)*q
    {
      const float b0 = bss[col0], b1 = bss[col1];
      f32x4 s0 = (f32x4){b0, b0, b0, b0};
      f32x4 s1 = (f32x4){b1, b1, b1, b1};
#pragma unroll
      for (int kt = 0; kt < 4; ++kt) {
        const f16x8 A = *reinterpret_cast<const f16x8*>(
            (const void*)&xs[lcol][(e + 1) * DD + kt * 32 + g8]);
        const f16x8 B0 = *reinterpret_cast<const f16x8*>(
            (const void*)(pws + ((size_t)(kt * 8 + nt0) * 512) + l * 8));
        const f16x8 B1 = *reinterpret_cast<const f16x8*>(
            (const void*)(pws + ((size_t)(kt * 8 + nt0 + 1) * 512) + l * 8));
        s0 = __builtin_amdgcn_mfma_f32_16x16x32_f16(A, B0, s0, 0, 0, 0);
        s1 = __builtin_amdgcn_mfma_f32_16x16x32_f16(A, B1, s1, 0, 0, 0);
      }
      const float q0 = qp[col0], q1 = qp[col1];
      float p[4];
#pragma unroll
      for (int j = 0; j < 4; ++j)
        p[j] = fast_tanh(s0[j]) * q0 + fast_tanh(s1[j]) * q1;
#pragma unroll
      for (int off = 1; off < 16; off <<= 1) {
#pragma unroll
        for (int j = 0; j < 4; ++j) p[j] += __shfl_xor(p[j], off, 64);
      }
      if (lcol == 0) {
        const int rbase = (l >> 4) << 2;
#pragma unroll
        for (int j = 0; j < 4; ++j) red[w][rbase + j] = p[j];
      }
    }
    __syncthreads();
    if (tid < TRR) {
      float s = red[0][tid] + red[1][tid] + red[2][tid] + red[3][tid];
#pragma unroll
      for (int off = 1; off < 16; off <<= 1) s += __shfl_xor(s, off, 64);
      if (tid == 0) atomicAdd(&wbase[(bl & 63) * 4 + e], s);
    }
    __syncthreads();
  }
}

// ---------------------------------------------------------------------------
__global__ void k_beta(const float* __restrict__ wsum, float* __restrict__ beta) {
  if (threadIdx.x == 0 && blockIdx.x == 0) {
    const float invN[3] = {1.f / 51200.f, 1.f / 1024.f, 1.f / 1024.f};
    for (int g = 0; g < 3; ++g) {
      float s0 = 0.f, s1 = 0.f, s2 = 0.f;
      for (int bkt = 0; bkt < 64; ++bkt) {
        s0 += wsum[g * 256 + bkt * 4 + 0];
        s1 += wsum[g * 256 + bkt * 4 + 1];
        s2 += wsum[g * 256 + bkt * 4 + 2];
      }
      s0 *= invN[g]; s1 *= invN[g]; s2 *= invN[g];
      const float mx = fmaxf(s0, fmaxf(s1, s2));
      const float e0 = expf(s0 - mx), e1 = expf(s1 - mx), e2 = expf(s2 - mx);
      const float inv = 1.f / (e0 + e1 + e2);
      beta[g * 4 + 0] = e0 * inv;
      beta[g * 4 + 1] = e1 * inv;
      beta[g * 4 + 2] = e2 * inv;
    }
  }
}

__global__ void k_out(const ushort_t* __restrict__ h, const float* __restrict__ beta,
                      float* __restrict__ out) {
  const int idx = blockIdx.x * blockDim.x + threadIdx.x;
  const int row = idx >> 7;
  const int g = (row < 51200) ? 0 : ((row < 52224) ? 1 : 2);
  const float* bt = beta + g * 4;
  const size_t base = (size_t)idx + (size_t)row * 2 * DD;
  UH a, b, c;
  a.s = h[base]; b.s = h[base + DD]; c.s = h[base + 2 * DD];
  out[idx] = bt[0] * __half2float(a.h) + bt[1] * __half2float(b.h) +
             bt[2] * __half2float(c.h);
}

// ---------------------------------------------------------------------------

extern "C" void kernel_launch(void* const* d_in, const int* in_sizes, int n_in,
                              void* d_out, int out_size, void* d_ws, size_t ws_size,
                              hipStream_t stream) {
  const int*   item     = (const int*)  d_in[0];
  const int*   locs     = (const int*)  d_in[1];
  const int*   times    = (const int*)  d_in[2];
  const float* session  = (const float*)d_in[3];
  const float* loc_emb  = (const float*)d_in[4];
  const float* time_emb = (const float*)d_in[5];
  const float* item_emb = (const float*)d_in[6];
  const int* nb_IL = (const int*)d_in[7];
  const int* nb_TL = (const int*)d_in[8];
  const int* nb_IT = (const int*)d_in[9];
  const int* nb_LT = (const int*)d_in[10];
  const int* nb_II = (const int*)d_in[11];
  const int* nb_LI = (const int*)d_in[12];
  const int* nb_TI = (const int*)d_in[13];
  const float* W_IL = (const float*)d_in[14]; const float* b_IL = (const float*)d_in[15];
  const float* W_TL = (const float*)d_in[16]; const float* b_TL = (const float*)d_in[17];
  const float* W_IT = (const float*)d_in[18]; const float* b_IT = (const float*)d_in[19];
  const float* W_LT = (const float*)d_in[20]; const float* b_LT = (const float*)d_in[21];
  const float* W_II = (const float*)d_in[22]; const float* b_II = (const float*)d_in[23];
  const float* W_LI = (const float*)d_in[24]; const float* b_LI = (const float*)d_in[25];
  const float* W_TI = (const float*)d_in[26]; const float* b_TI = (const float*)d_in[27];
  const float* Ws_l = (const float*)d_in[28]; const float* bs_l = (const float*)d_in[29];
  const float* q_l  = (const float*)d_in[30];
  const float* Ws_t = (const float*)d_in[31]; const float* bs_t = (const float*)d_in[32];
  const float* q_t  = (const float*)d_in[33];
  const float* Ws_i = (const float*)d_in[34]; const float* bs_i = (const float*)d_in[35];
  const float* q_i  = (const float*)d_in[36];

  float* outp = (float*)d_out;

  // ws: wsum/beta(16K) | packed W(544K) | hbuf fp16(40.9M) | fp16 tables(28.7M)
  char* wsb = (char*)d_ws;
  float* wsum  = (float*)wsb;
  float* betap = (float*)wsb + 1024;
  ushort_t* pk = (ushort_t*)(wsb + 16384);
  ushort_t* pk_II = pk;
  ushort_t* pk_TI = pk_II + 32768;
  ushort_t* pk_LI = pk_TI + 32768;
  ushort_t* pk_IL = pk_LI + 32768;
  ushort_t* pk_TL = pk_IL + 32768;
  ushort_t* pk_IT = pk_TL + 32768;
  ushort_t* pk_LT = pk_IT + 32768;
  ushort_t* pk_Wi = pk_LT + 32768;
  ushort_t* pk_Wl = pk_Wi + 16384;
  ushort_t* pk_Wt = pk_Wl + 16384;
  ushort_t* hbuf  = pk_Wt + 16384;
  ushort_t* item_h = hbuf + (size_t)53248 * 3 * DD;
  ushort_t* loc_h  = item_h + (size_t)100000 * DD;
  ushort_t* time_h = loc_h + (size_t)10000 * DD;

  hipMemsetAsync(d_ws, 0, 16384, stream);

  CvtArgs ca;
  ca.item = item_emb; ca.loc = loc_emb; ca.timet = time_emb; ca.dst = item_h;
  k_cvt3<<<dim3(7000), dim3(256), 0, stream>>>(ca);

  PackArgs pa;
  pa.src[0] = W_II; pa.src[1] = W_TI; pa.src[2] = W_LI;
  pa.src[3] = W_IL; pa.src[4] = W_TL; pa.src[5] = W_IT; pa.src[6] = W_LT;
  pa.src[7] = Ws_i; pa.src[8] = Ws_l; pa.src[9] = Ws_t;
  pa.dst = pk;
  k_pack10<<<dim3(136), dim3(256), 0, stream>>>(pa);

  ushort_t* h_items = hbuf;
  ushort_t* h_locs  = hbuf + (size_t)51200 * 3 * DD;
  ushort_t* h_times = hbuf + (size_t)52224 * 3 * DD;

  MegaArgs ma;
  ma.item_idx = item; ma.item_t = item_h;
  ma.nbI[0] = nb_II; ma.nbI[1] = nb_TI; ma.nbI[2] = nb_LI;
  ma.embI[0] = item_h; ma.embI[1] = time_h; ma.embI[2] = loc_h;
  ma.pWI[0] = pk_II; ma.pWI[1] = pk_TI; ma.pWI[2] = pk_LI;
  ma.bI[0] = b_II; ma.bI[1] = b_TI; ma.bI[2] = b_LI;
  ma.pWsI = pk_Wi; ma.bsI = bs_i; ma.qI = q_i;
  ma.hI = h_items; ma.wsumI = wsum + 0;
  ma.sidx[0] = locs;  ma.sidx[1] = times;
  ma.st[0] = loc_h;   ma.st[1] = time_h;
  ma.nbS[0][0] = nb_IL; ma.nbS[0][1] = nb_TL;
  ma.nbS[1][0] = nb_IT; ma.nbS[1][1] = nb_LT;
  ma.embS[0][0] = item_h; ma.embS[0][1] = time_h;
  ma.embS[1][0] = item_h; ma.embS[1][1] = loc_h;
  ma.pWS[0][0] = pk_IL; ma.pWS[0][1] = pk_TL;
  ma.pWS[1][0] = pk_IT; ma.pWS[1][1] = pk_LT;
  ma.bS[0][0] = b_IL; ma.bS[0][1] = b_TL;
  ma.bS[1][0] = b_IT; ma.bS[1][1] = b_LT;
  ma.pWsS[0] = pk_Wl; ma.pWsS[1] = pk_Wt;
  ma.bsS[0] = bs_l; ma.bsS[1] = bs_t;
  ma.qS[0] = q_l; ma.qS[1] = q_t;
  ma.session = session;
  ma.hS[0] = h_locs; ma.hS[1] = h_times;
  ma.wsumS[0] = wsum + 256; ma.wsumS[1] = wsum + 512;
  k_mega<<<dim3(128 + 51200 / TRR), dim3(256), 0, stream>>>(ma);

  k_beta<<<dim3(1), dim3(64), 0, stream>>>(wsum, betap);
  k_out<<<dim3((53248 * 128) / 256), dim3(256), 0, stream>>>(hbuf, betap, outp);
}

// Round 9
// 124.874 us; speedup vs baseline: 5.0479x; 1.1641x over previous
//
#include <hip/hip_runtime.h>
#include <hip/hip_fp16.h>

#define DD 128
#define KK 20
#define TRR 16

typedef unsigned int uint_t;
typedef unsigned short ushort_t;
typedef unsigned char uchar_t;
typedef _Float16 f16x8 __attribute__((ext_vector_type(8)));
typedef _Float16 f16x2 __attribute__((ext_vector_type(2)));
typedef float f32x4 __attribute__((ext_vector_type(4)));
typedef float f32x2 __attribute__((ext_vector_type(2)));

union UH { __half h; ushort_t s; };
union UF { f16x2 v[4]; uint4 u4; };

__device__ __forceinline__ float fast_tanh(float x) {
  const float e = __expf(2.f * x);
  return 1.f - 2.f / (e + 1.f);
}

// unpack 8 fp8 (uint2) -> accumulate into 4 packed f16x2
__device__ __forceinline__ void f8acc(f16x2* a, const uint2 v) {
  f32x2 p;
  p = __builtin_amdgcn_cvt_pk_f32_fp8(v.x, false);
  a[0] += __builtin_amdgcn_cvt_pkrtz(p[0], p[1]);
  p = __builtin_amdgcn_cvt_pk_f32_fp8(v.x, true);
  a[1] += __builtin_amdgcn_cvt_pkrtz(p[0], p[1]);
  p = __builtin_amdgcn_cvt_pk_f32_fp8(v.y, false);
  a[2] += __builtin_amdgcn_cvt_pkrtz(p[0], p[1]);
  p = __builtin_amdgcn_cvt_pk_f32_fp8(v.y, true);
  a[3] += __builtin_amdgcn_cvt_pkrtz(p[0], p[1]);
}

// ---------------------------------------------------------------------------
// k_cvt3: three f32 tables -> fp16 region (self reads) + fp8 region (gathers)
// ---------------------------------------------------------------------------
struct CvtArgs {
  const float* item; const float* loc; const float* timet;
  ushort_t* dst16; uchar_t* dst8;
};

__global__ __launch_bounds__(256)
void k_cvt3(CvtArgs a) {
  const int t = blockIdx.x * blockDim.x + threadIdx.x;  // 7000*256 = 1,792,000
  const float* src;
  if (t < 1600000) src = a.item + (size_t)t * 8;
  else if (t < 1760000) src = a.loc + ((size_t)t - 1600000) * 8;
  else src = a.timet + ((size_t)t - 1760000) * 8;
  const float4* ip = reinterpret_cast<const float4*>(src);
  const float4 x = ip[0], y = ip[1];
  UH h[8];
  h[0].h = __float2half_rn(x.x); h[1].h = __float2half_rn(x.y);
  h[2].h = __float2half_rn(x.z); h[3].h = __float2half_rn(x.w);
  h[4].h = __float2half_rn(y.x); h[5].h = __float2half_rn(y.y);
  h[6].h = __float2half_rn(y.z); h[7].h = __float2half_rn(y.w);
  uint4 o;
  o.x = (uint_t)h[0].s | ((uint_t)h[1].s << 16);
  o.y = (uint_t)h[2].s | ((uint_t)h[3].s << 16);
  o.z = (uint_t)h[4].s | ((uint_t)h[5].s << 16);
  o.w = (uint_t)h[6].s | ((uint_t)h[7].s << 16);
  reinterpret_cast<uint4*>(a.dst16)[t] = o;
  uint_t p0 = __builtin_amdgcn_cvt_pk_fp8_f32(x.x, x.y, 0u, false);
  p0 = __builtin_amdgcn_cvt_pk_fp8_f32(x.z, x.w, p0, true);
  uint_t p1 = __builtin_amdgcn_cvt_pk_fp8_f32(y.x, y.y, 0u, false);
  p1 = __builtin_amdgcn_cvt_pk_fp8_f32(y.z, y.w, p1, true);
  uint2 q; q.x = p0; q.y = p1;
  reinterpret_cast<uint2*>(a.dst8)[t] = q;
}

// ---------------------------------------------------------------------------
// k_pack10: all 10 weight matrices -> MFMA B-fragment order fp16.
// Fragment (kt,nt): lane l, reg j <- W[kt*32 + (l>>4)*8 + j][nt*16 + (l&15)]
// ---------------------------------------------------------------------------
struct PackArgs {
  const float* src[10];
  ushort_t* dst;
};

__global__ __launch_bounds__(256)
void k_pack10(PackArgs a) {
  const int b = blockIdx.x, tid = threadIdx.x;
  int job, tin;
  size_t doff;
  if (b < 112) {
    job = b >> 4; tin = ((b & 15) << 8) | tid;
    doff = (size_t)job * 32768;
  } else {
    job = 7 + ((b - 112) >> 3); tin = (((b - 112) & 7) << 8) | tid;
    doff = 7ull * 32768 + (size_t)(job - 7) * 16384;
  }
  const float* W = a.src[job];
  const int l = tin & 63;
  const int ktnt = tin >> 6;
  const int nt = ktnt & 7;
  const int kt = ktnt >> 3;
  const int col = nt * 16 + (l & 15);
  const int kb = kt * 32 + ((l >> 4) << 3);
  UH h[8];
#pragma unroll
  for (int j = 0; j < 8; ++j) h[j].h = __float2half_rn(W[(size_t)(kb + j) * DD + col]);
  uint4 o;
  o.x = (uint_t)h[0].s | ((uint_t)h[1].s << 16);
  o.y = (uint_t)h[2].s | ((uint_t)h[3].s << 16);
  o.z = (uint_t)h[4].s | ((uint_t)h[5].s << 16);
  o.w = (uint_t)h[6].s | ((uint_t)h[7].s << 16);
  *reinterpret_cast<uint4*>(a.dst + doff + (size_t)ktnt * 512 + l * 8) = o;
}

// ---------------------------------------------------------------------------
// k_mega: whole graph in one kernel. fp8 neighbor gathers (f16x2 accumulate),
// fp16 self rows + MFMA path. launch_bounds(256,6): reg cap ~85 — the f16x2
// accumulator form needs ~60 live regs (R7 lesson: f32 acc spilled at cap 73).
// ---------------------------------------------------------------------------
struct MegaArgs {
  // items
  const int* item_idx; const ushort_t* item_t;
  const int* nbI[3]; const uchar_t* embI[3]; const ushort_t* pWI[3]; const float* bI[3];
  const ushort_t* pWsI; const float* bsI; const float* qI;
  ushort_t* hI; float* wsumI;
  // locs (g=0) / times (g=1)
  const int* sidx[2]; const ushort_t* st[2];
  const int* nbS[2][2]; const uchar_t* embS[2][2];
  const ushort_t* pWS[2][2]; const float* bS[2][2];
  const ushort_t* pWsS[2]; const float* bsS[2]; const float* qS[2];
  const float* session;
  ushort_t* hS[2]; float* wsumS[2];
};

__global__ __launch_bounds__(256, 6)
void k_mega(MegaArgs a) {
  __shared__ int ids[TRR];
  __shared__ int nidx[3][TRR][KK];
  __shared__ __align__(16) ushort_t xs[TRR][4 * DD + 8];   // 520: self|s1|s2|s3
  __shared__ float red[4][TRR];

  const int tid = threadIdx.x;
  const int l = tid & 63;
  const int w = tid >> 6;
  const int bid = blockIdx.x;

  const bool isS = bid < 128;
  const int g = isS ? (bid >> 6) : 0;
  const int bl = isS ? (bid & 63) : (bid - 128);
  const int n0 = bl * TRR;

  const int* sidx;
  const ushort_t* selft;
  const int* nb_[3];
  const uchar_t* emb_[3];
  const ushort_t* pW_[3];
  const float* bias_[3];
  const ushort_t* pws; const float* bss; const float* qp;
  ushort_t* hd; float* wbase;
  if (!isS) {
    sidx = a.item_idx; selft = a.item_t;
    nb_[0] = a.nbI[0]; nb_[1] = a.nbI[1]; nb_[2] = a.nbI[2];
    emb_[0] = a.embI[0]; emb_[1] = a.embI[1]; emb_[2] = a.embI[2];
    pW_[0] = a.pWI[0]; pW_[1] = a.pWI[1]; pW_[2] = a.pWI[2];
    bias_[0] = a.bI[0]; bias_[1] = a.bI[1]; bias_[2] = a.bI[2];
    pws = a.pWsI; bss = a.bsI; qp = a.qI;
    hd = a.hI; wbase = a.wsumI;
  } else if (g == 0) {
    sidx = a.sidx[0]; selft = a.st[0];
    nb_[0] = a.nbS[0][0]; nb_[1] = a.nbS[0][1]; nb_[2] = nullptr;
    emb_[0] = a.embS[0][0]; emb_[1] = a.embS[0][1]; emb_[2] = nullptr;
    pW_[0] = a.pWS[0][0]; pW_[1] = a.pWS[0][1]; pW_[2] = nullptr;
    bias_[0] = a.bS[0][0]; bias_[1] = a.bS[0][1]; bias_[2] = nullptr;
    pws = a.pWsS[0]; bss = a.bsS[0]; qp = a.qS[0];
    hd = a.hS[0]; wbase = a.wsumS[0];
  } else {
    sidx = a.sidx[1]; selft = a.st[1];
    nb_[0] = a.nbS[1][0]; nb_[1] = a.nbS[1][1]; nb_[2] = nullptr;
    emb_[0] = a.embS[1][0]; emb_[1] = a.embS[1][1]; emb_[2] = nullptr;
    pW_[0] = a.pWS[1][0]; pW_[1] = a.pWS[1][1]; pW_[2] = nullptr;
    bias_[0] = a.bS[1][0]; bias_[1] = a.bS[1][1]; bias_[2] = nullptr;
    pws = a.pWsS[1]; bss = a.bsS[1]; qp = a.qS[1];
    hd = a.hS[1]; wbase = a.wsumS[1];
  }

  if (tid < TRR) ids[tid] = sidx[n0 + tid];
  __syncthreads();

  const int gr = tid >> 4;        // row 0..15
  const int gsl = tid & 15;       // 8-elem slice within a row

  // stage neighbor index lists (edge-major)
#pragma unroll
  for (int e = 0; e < 3; ++e) {
    if (nb_[e]) {
      for (int t = tid; t < TRR * KK; t += 256) {
        const int rr = t / KK, kk = t - rr * KK;
        nidx[e][rr][kk] = nb_[e][(size_t)ids[rr] * KK + kk];
      }
    }
  }
  // self half of x (fp16 table)
  *reinterpret_cast<uint4*>(&xs[gr][gsl * 8]) =
      *reinterpret_cast<const uint4*>(selft + ((size_t)ids[gr] << 7) + gsl * 8);
  __syncthreads();

  // ---- concurrent fp8 gathers for all edges, f16x2 accumulation ----
  if (!isS) {
    UF A0, A1, A2;
#pragma unroll
    for (int i = 0; i < 4; ++i) {
      A0.v[i] = (f16x2)0; A1.v[i] = (f16x2)0; A2.v[i] = (f16x2)0;
    }
#pragma unroll
    for (int kb = 0; kb < KK; kb += 4) {
      uint2 u0[4], u1[4], u2[4];
#pragma unroll
      for (int j = 0; j < 4; ++j)
        u0[j] = *reinterpret_cast<const uint2*>(emb_[0] + ((size_t)nidx[0][gr][kb + j] << 7) + gsl * 8);
#pragma unroll
      for (int j = 0; j < 4; ++j)
        u1[j] = *reinterpret_cast<const uint2*>(emb_[1] + ((size_t)nidx[1][gr][kb + j] << 7) + gsl * 8);
#pragma unroll
      for (int j = 0; j < 4; ++j)
        u2[j] = *reinterpret_cast<const uint2*>(emb_[2] + ((size_t)nidx[2][gr][kb + j] << 7) + gsl * 8);
#pragma unroll
      for (int j = 0; j < 4; ++j) {
        f8acc(A0.v, u0[j]); f8acc(A1.v, u1[j]); f8acc(A2.v, u2[j]);
      }
    }
    const _Float16 sch = (_Float16)(1.f / KK);
    const f16x2 scv = (f16x2){sch, sch};
#pragma unroll
    for (int i = 0; i < 4; ++i) {
      A0.v[i] *= scv; A1.v[i] *= scv; A2.v[i] *= scv;
    }
    *reinterpret_cast<uint4*>(&xs[gr][1 * DD + gsl * 8]) = A0.u4;
    *reinterpret_cast<uint4*>(&xs[gr][2 * DD + gsl * 8]) = A1.u4;
    *reinterpret_cast<uint4*>(&xs[gr][3 * DD + gsl * 8]) = A2.u4;
  } else {
    UF A0, A1;
#pragma unroll
    for (int i = 0; i < 4; ++i) { A0.v[i] = (f16x2)0; A1.v[i] = (f16x2)0; }
#pragma unroll
    for (int kb = 0; kb < KK; kb += 5) {
      uint2 u0[5], u1[5];
#pragma unroll
      for (int j = 0; j < 5; ++j)
        u0[j] = *reinterpret_cast<const uint2*>(emb_[0] + ((size_t)nidx[0][gr][kb + j] << 7) + gsl * 8);
#pragma unroll
      for (int j = 0; j < 5; ++j)
        u1[j] = *reinterpret_cast<const uint2*>(emb_[1] + ((size_t)nidx[1][gr][kb + j] << 7) + gsl * 8);
#pragma unroll
      for (int j = 0; j < 5; ++j) { f8acc(A0.v, u0[j]); f8acc(A1.v, u1[j]); }
    }
    const _Float16 sch = (_Float16)(1.f / KK);
    const f16x2 scv = (f16x2){sch, sch};
#pragma unroll
    for (int i = 0; i < 4; ++i) { A0.v[i] *= scv; A1.v[i] *= scv; }
    *reinterpret_cast<uint4*>(&xs[gr][1 * DD + gsl * 8]) = A0.u4;
    *reinterpret_cast<uint4*>(&xs[gr][2 * DD + gsl * 8]) = A1.u4;
    // session -> slot 3 (fp16) + hbuf m=2
    const float* srow = a.session + (size_t)(n0 + gr) * DD + gsl * 8;
    const float4 v0 = *reinterpret_cast<const float4*>(srow);
    const float4 v1 = *reinterpret_cast<const float4*>(srow + 4);
    UH h0, h1, h2, h3, h4, h5, h6, h7;
    h0.h = __float2half_rn(v0.x); h1.h = __float2half_rn(v0.y);
    h2.h = __float2half_rn(v0.z); h3.h = __float2half_rn(v0.w);
    h4.h = __float2half_rn(v1.x); h5.h = __float2half_rn(v1.y);
    h6.h = __float2half_rn(v1.z); h7.h = __float2half_rn(v1.w);
    uint4 o;
    o.x = (uint_t)h0.s | ((uint_t)h1.s << 16);
    o.y = (uint_t)h2.s | ((uint_t)h3.s << 16);
    o.z = (uint_t)h4.s | ((uint_t)h5.s << 16);
    o.w = (uint_t)h6.s | ((uint_t)h7.s << 16);
    *reinterpret_cast<uint4*>(&xs[gr][3 * DD + gsl * 8]) = o;
    *reinterpret_cast<uint4*>(hd + (size_t)(n0 + gr) * 3 * DD + 2 * DD + gsl * 8) = o;
  }
  __syncthreads();

  // ---- per-edge MFMA + score ----
  const int nt0 = 2 * w;
  const int lcol = l & 15;
  const int g8 = (l >> 4) << 3;
  const int col0 = nt0 * 16 + lcol;
  const int col1 = col0 + 16;

#pragma unroll
  for (int e = 0; e < 3; ++e) {
    const bool full = (!isS) || (e < 2);
    if (full) {
      const ushort_t* pWp = pW_[e];
      const float* bp = bias_[e];
      f32x4 acc0, acc1;
      {
        const float b0 = bp[col0], b1 = bp[col1];
        acc0 = (f32x4){b0, b0, b0, b0};
        acc1 = (f32x4){b1, b1, b1, b1};
#pragma unroll
        for (int kt = 0; kt < 8; ++kt) {
          const int xcol = (kt < 4) ? (kt * 32 + g8) : (e * DD + kt * 32 + g8);
          const f16x8 A = *reinterpret_cast<const f16x8*>((const void*)&xs[lcol][xcol]);
          const f16x8 B0 = *reinterpret_cast<const f16x8*>(
              (const void*)(pWp + ((size_t)(kt * 8 + nt0) * 512) + l * 8));
          const f16x8 B1 = *reinterpret_cast<const f16x8*>(
              (const void*)(pWp + ((size_t)(kt * 8 + nt0 + 1) * 512) + l * 8));
          acc0 = __builtin_amdgcn_mfma_f32_16x16x32_f16(A, B0, acc0, 0, 0, 0);
          acc1 = __builtin_amdgcn_mfma_f32_16x16x32_f16(A, B1, acc1, 0, 0, 0);
        }
#pragma unroll
        for (int j = 0; j < 4; ++j) {
          acc0[j] = fmaxf(acc0[j], 0.f);
          acc1[j] = fmaxf(acc1[j], 0.f);
        }
      }
      __syncthreads();  // all A-reads of slot e+1 done before overwrite
      {
        const int rbase = (l >> 4) << 2;
#pragma unroll
        for (int j = 0; j < 4; ++j) {
          const int row = rbase + j;
          UH h0, h1;
          h0.h = __float2half_rn(acc0[j]);
          h1.h = __float2half_rn(acc1[j]);
          hd[(size_t)(n0 + row) * 3 * DD + e * DD + col0] = h0.s;
          hd[(size_t)(n0 + row) * 3 * DD + e * DD + col1] = h1.s;
          xs[row][(e + 1) * DD + col0] = h0.s;
          xs[row][(e + 1) * DD + col1] = h1.s;
        }
      }
      __syncthreads();  // h visible in LDS
    }
    // score: t = h @ Ws + bs; w = sum_cols tanh(t)*q
    {
      const float b0 = bss[col0], b1 = bss[col1];
      f32x4 s0 = (f32x4){b0, b0, b0, b0};
      f32x4 s1 = (f32x4){b1, b1, b1, b1};
#pragma unroll
      for (int kt = 0; kt < 4; ++kt) {
        const f16x8 A = *reinterpret_cast<const f16x8*>(
            (const void*)&xs[lcol][(e + 1) * DD + kt * 32 + g8]);
        const f16x8 B0 = *reinterpret_cast<const f16x8*>(
            (const void*)(pws + ((size_t)(kt * 8 + nt0) * 512) + l * 8));
        const f16x8 B1 = *reinterpret_cast<const f16x8*>(
            (const void*)(pws + ((size_t)(kt * 8 + nt0 + 1) * 512) + l * 8));
        s0 = __builtin_amdgcn_mfma_f32_16x16x32_f16(A, B0, s0, 0, 0, 0);
        s1 = __builtin_amdgcn_mfma_f32_16x16x32_f16(A, B1, s1, 0, 0, 0);
      }
      const float q0 = qp[col0], q1 = qp[col1];
      float p[4];
#pragma unroll
      for (int j = 0; j < 4; ++j)
        p[j] = fast_tanh(s0[j]) * q0 + fast_tanh(s1[j]) * q1;
#pragma unroll
      for (int off = 1; off < 16; off <<= 1) {
#pragma unroll
        for (int j = 0; j < 4; ++j) p[j] += __shfl_xor(p[j], off, 64);
      }
      if (lcol == 0) {
        const int rbase = (l >> 4) << 2;
#pragma unroll
        for (int j = 0; j < 4; ++j) red[w][rbase + j] = p[j];
      }
    }
    __syncthreads();
    if (tid < TRR) {
      float s = red[0][tid] + red[1][tid] + red[2][tid] + red[3][tid];
#pragma unroll
      for (int off = 1; off < 16; off <<= 1) s += __shfl_xor(s, off, 64);
      if (tid == 0) atomicAdd(&wbase[(bl & 63) * 4 + e], s);
    }
    __syncthreads();
  }
}

// ---------------------------------------------------------------------------
__global__ void k_beta(const float* __restrict__ wsum, float* __restrict__ beta) {
  if (threadIdx.x == 0 && blockIdx.x == 0) {
    const float invN[3] = {1.f / 51200.f, 1.f / 1024.f, 1.f / 1024.f};
    for (int g = 0; g < 3; ++g) {
      float s0 = 0.f, s1 = 0.f, s2 = 0.f;
      for (int bkt = 0; bkt < 64; ++bkt) {
        s0 += wsum[g * 256 + bkt * 4 + 0];
        s1 += wsum[g * 256 + bkt * 4 + 1];
        s2 += wsum[g * 256 + bkt * 4 + 2];
      }
      s0 *= invN[g]; s1 *= invN[g]; s2 *= invN[g];
      const float mx = fmaxf(s0, fmaxf(s1, s2));
      const float e0 = expf(s0 - mx), e1 = expf(s1 - mx), e2 = expf(s2 - mx);
      const float inv = 1.f / (e0 + e1 + e2);
      beta[g * 4 + 0] = e0 * inv;
      beta[g * 4 + 1] = e1 * inv;
      beta[g * 4 + 2] = e2 * inv;
    }
  }
}

__global__ void k_out(const ushort_t* __restrict__ h, const float* __restrict__ beta,
                      float* __restrict__ out) {
  const int idx = blockIdx.x * blockDim.x + threadIdx.x;
  const int row = idx >> 7;
  const int g = (row < 51200) ? 0 : ((row < 52224) ? 1 : 2);
  const float* bt = beta + g * 4;
  const size_t base = (size_t)idx + (size_t)row * 2 * DD;
  UH a, b, c;
  a.s = h[base]; b.s = h[base + DD]; c.s = h[base + 2 * DD];
  out[idx] = bt[0] * __half2float(a.h) + bt[1] * __half2float(b.h) +
             bt[2] * __half2float(c.h);
}

// ---------------------------------------------------------------------------

extern "C" void kernel_launch(void* const* d_in, const int* in_sizes, int n_in,
                              void* d_out, int out_size, void* d_ws, size_t ws_size,
                              hipStream_t stream) {
  const int*   item     = (const int*)  d_in[0];
  const int*   locs     = (const int*)  d_in[1];
  const int*   times    = (const int*)  d_in[2];
  const float* session  = (const float*)d_in[3];
  const float* loc_emb  = (const float*)d_in[4];
  const float* time_emb = (const float*)d_in[5];
  const float* item_emb = (const float*)d_in[6];
  const int* nb_IL = (const int*)d_in[7];
  const int* nb_TL = (const int*)d_in[8];
  const int* nb_IT = (const int*)d_in[9];
  const int* nb_LT = (const int*)d_in[10];
  const int* nb_II = (const int*)d_in[11];
  const int* nb_LI = (const int*)d_in[12];
  const int* nb_TI = (const int*)d_in[13];
  const float* W_IL = (const float*)d_in[14]; const float* b_IL = (const float*)d_in[15];
  const float* W_TL = (const float*)d_in[16]; const float* b_TL = (const float*)d_in[17];
  const float* W_IT = (const float*)d_in[18]; const float* b_IT = (const float*)d_in[19];
  const float* W_LT = (const float*)d_in[20]; const float* b_LT = (const float*)d_in[21];
  const float* W_II = (const float*)d_in[22]; const float* b_II = (const float*)d_in[23];
  const float* W_LI = (const float*)d_in[24]; const float* b_LI = (const float*)d_in[25];
  const float* W_TI = (const float*)d_in[26]; const float* b_TI = (const float*)d_in[27];
  const float* Ws_l = (const float*)d_in[28]; const float* bs_l = (const float*)d_in[29];
  const float* q_l  = (const float*)d_in[30];
  const float* Ws_t = (const float*)d_in[31]; const float* bs_t = (const float*)d_in[32];
  const float* q_t  = (const float*)d_in[33];
  const float* Ws_i = (const float*)d_in[34]; const float* bs_i = (const float*)d_in[35];
  const float* q_i  = (const float*)d_in[36];

  float* outp = (float*)d_out;

  // ws: wsum/beta(16K) | packed W(544K) | hbuf fp16(40.9M) | fp16 tables(28.7M)
  //     | fp8 tables(14.3M)  -- ~84.5MB total (R7 ran this layout: ws fits)
  char* wsb = (char*)d_ws;
  float* wsum  = (float*)wsb;
  float* betap = (float*)wsb + 1024;
  ushort_t* pk = (ushort_t*)(wsb + 16384);
  ushort_t* pk_II = pk;
  ushort_t* pk_TI = pk_II + 32768;
  ushort_t* pk_LI = pk_TI + 32768;
  ushort_t* pk_IL = pk_LI + 32768;
  ushort_t* pk_TL = pk_IL + 32768;
  ushort_t* pk_IT = pk_TL + 32768;
  ushort_t* pk_LT = pk_IT + 32768;
  ushort_t* pk_Wi = pk_LT + 32768;
  ushort_t* pk_Wl = pk_Wi + 16384;
  ushort_t* pk_Wt = pk_Wl + 16384;
  ushort_t* hbuf  = pk_Wt + 16384;
  ushort_t* item_h = hbuf + (size_t)53248 * 3 * DD;
  ushort_t* loc_h  = item_h + (size_t)100000 * DD;
  ushort_t* time_h = loc_h + (size_t)10000 * DD;
  uchar_t* item_8 = (uchar_t*)(time_h + (size_t)2000 * DD);
  uchar_t* loc_8  = item_8 + (size_t)100000 * DD;
  uchar_t* time_8 = loc_8 + (size_t)10000 * DD;

  hipMemsetAsync(d_ws, 0, 16384, stream);

  CvtArgs ca;
  ca.item = item_emb; ca.loc = loc_emb; ca.timet = time_emb;
  ca.dst16 = item_h; ca.dst8 = item_8;
  k_cvt3<<<dim3(7000), dim3(256), 0, stream>>>(ca);

  PackArgs pa;
  pa.src[0] = W_II; pa.src[1] = W_TI; pa.src[2] = W_LI;
  pa.src[3] = W_IL; pa.src[4] = W_TL; pa.src[5] = W_IT; pa.src[6] = W_LT;
  pa.src[7] = Ws_i; pa.src[8] = Ws_l; pa.src[9] = Ws_t;
  pa.dst = pk;
  k_pack10<<<dim3(136), dim3(256), 0, stream>>>(pa);

  ushort_t* h_items = hbuf;
  ushort_t* h_locs  = hbuf + (size_t)51200 * 3 * DD;
  ushort_t* h_times = hbuf + (size_t)52224 * 3 * DD;

  MegaArgs ma;
  ma.item_idx = item; ma.item_t = item_h;
  ma.nbI[0] = nb_II; ma.nbI[1] = nb_TI; ma.nbI[2] = nb_LI;
  ma.embI[0] = item_8; ma.embI[1] = time_8; ma.embI[2] = loc_8;
  ma.pWI[0] = pk_II; ma.pWI[1] = pk_TI; ma.pWI[2] = pk_LI;
  ma.bI[0] = b_II; ma.bI[1] = b_TI; ma.bI[2] = b_LI;
  ma.pWsI = pk_Wi; ma.bsI = bs_i; ma.qI = q_i;
  ma.hI = h_items; ma.wsumI = wsum + 0;
  ma.sidx[0] = locs;  ma.sidx[1] = times;
  ma.st[0] = loc_h;   ma.st[1] = time_h;
  ma.nbS[0][0] = nb_IL; ma.nbS[0][1] = nb_TL;
  ma.nbS[1][0] = nb_IT; ma.nbS[1][1] = nb_LT;
  ma.embS[0][0] = item_8; ma.embS[0][1] = time_8;
  ma.embS[1][0] = item_8; ma.embS[1][1] = loc_8;
  ma.pWS[0][0] = pk_IL; ma.pWS[0][1] = pk_TL;
  ma.pWS[1][0] = pk_IT; ma.pWS[1][1] = pk_LT;
  ma.bS[0][0] = b_IL; ma.bS[0][1] = b_TL;
  ma.bS[1][0] = b_IT; ma.bS[1][1] = b_LT;
  ma.pWsS[0] = pk_Wl; ma.pWsS[1] = pk_Wt;
  ma.bsS[0] = bs_l; ma.bsS[1] = bs_t;
  ma.qS[0] = q_l; ma.qS[1] = q_t;
  ma.session = session;
  ma.hS[0] = h_locs; ma.hS[1] = h_times;
  ma.wsumS[0] = wsum + 256; ma.wsumS[1] = wsum + 512;
  k_mega<<<dim3(128 + 51200 / TRR), dim3(256), 0, stream>>>(ma);

  k_beta<<<dim3(1), dim3(64), 0, stream>>>(wsum, betap);
  k_out<<<dim3((53248 * 128) / 256), dim3(256), 0, stream>>>(hbuf, betap, outp);
}

// Round 10
// 123.554 us; speedup vs baseline: 5.1018x; 1.0107x over previous
//
#include <hip/hip_runtime.h>
#include <hip/hip_fp16.h>

#define DD 128
#define KK 20
#define TRR 16

typedef unsigned int uint_t;
typedef unsigned short ushort_t;
typedef unsigned char uchar_t;
typedef _Float16 f16x8 __attribute__((ext_vector_type(8)));
typedef _Float16 f16x2 __attribute__((ext_vector_type(2)));
typedef float f32x4 __attribute__((ext_vector_type(4)));
typedef float f32x2 __attribute__((ext_vector_type(2)));

union UH { __half h; ushort_t s; };
union UF { f16x2 v[4]; uint4 u4; };

#if __has_builtin(__builtin_amdgcn_cvt_scalef32_pk_f16_fp8)
#define HAVE_SCALEF32 1
#endif

__device__ __forceinline__ float fast_tanh(float x) {
  const float e = __expf(2.f * x);
  return 1.f - 2.f / (e + 1.f);
}

// unpack 8 fp8 (uint2) -> accumulate into 4 packed f16x2.
// scalef32 path: 1 op per 2 elems (scale=1.0 is exact; e4m3 subset of f16).
__device__ __forceinline__ void f8acc(f16x2* a, const uint2 v) {
#ifdef HAVE_SCALEF32
  a[0] += __builtin_amdgcn_cvt_scalef32_pk_f16_fp8(v.x, 1.0f, false);
  a[1] += __builtin_amdgcn_cvt_scalef32_pk_f16_fp8(v.x, 1.0f, true);
  a[2] += __builtin_amdgcn_cvt_scalef32_pk_f16_fp8(v.y, 1.0f, false);
  a[3] += __builtin_amdgcn_cvt_scalef32_pk_f16_fp8(v.y, 1.0f, true);
#else
  f32x2 p;
  p = __builtin_amdgcn_cvt_pk_f32_fp8(v.x, false);
  a[0] += __builtin_amdgcn_cvt_pkrtz(p[0], p[1]);
  p = __builtin_amdgcn_cvt_pk_f32_fp8(v.x, true);
  a[1] += __builtin_amdgcn_cvt_pkrtz(p[0], p[1]);
  p = __builtin_amdgcn_cvt_pk_f32_fp8(v.y, false);
  a[2] += __builtin_amdgcn_cvt_pkrtz(p[0], p[1]);
  p = __builtin_amdgcn_cvt_pk_f32_fp8(v.y, true);
  a[3] += __builtin_amdgcn_cvt_pkrtz(p[0], p[1]);
#endif
}

// ---------------------------------------------------------------------------
// k_cvt3: three f32 tables -> fp16 region (self reads) + fp8 region (gathers)
// ---------------------------------------------------------------------------
struct CvtArgs {
  const float* item; const float* loc; const float* timet;
  ushort_t* dst16; uchar_t* dst8;
};

__global__ __launch_bounds__(256)
void k_cvt3(CvtArgs a) {
  const int t = blockIdx.x * blockDim.x + threadIdx.x;  // 7000*256 = 1,792,000
  const float* src;
  if (t < 1600000) src = a.item + (size_t)t * 8;
  else if (t < 1760000) src = a.loc + ((size_t)t - 1600000) * 8;
  else src = a.timet + ((size_t)t - 1760000) * 8;
  const float4* ip = reinterpret_cast<const float4*>(src);
  const float4 x = ip[0], y = ip[1];
  UH h[8];
  h[0].h = __float2half_rn(x.x); h[1].h = __float2half_rn(x.y);
  h[2].h = __float2half_rn(x.z); h[3].h = __float2half_rn(x.w);
  h[4].h = __float2half_rn(y.x); h[5].h = __float2half_rn(y.y);
  h[6].h = __float2half_rn(y.z); h[7].h = __float2half_rn(y.w);
  uint4 o;
  o.x = (uint_t)h[0].s | ((uint_t)h[1].s << 16);
  o.y = (uint_t)h[2].s | ((uint_t)h[3].s << 16);
  o.z = (uint_t)h[4].s | ((uint_t)h[5].s << 16);
  o.w = (uint_t)h[6].s | ((uint_t)h[7].s << 16);
  reinterpret_cast<uint4*>(a.dst16)[t] = o;
  uint_t p0 = __builtin_amdgcn_cvt_pk_fp8_f32(x.x, x.y, 0u, false);
  p0 = __builtin_amdgcn_cvt_pk_fp8_f32(x.z, x.w, p0, true);
  uint_t p1 = __builtin_amdgcn_cvt_pk_fp8_f32(y.x, y.y, 0u, false);
  p1 = __builtin_amdgcn_cvt_pk_fp8_f32(y.z, y.w, p1, true);
  uint2 q; q.x = p0; q.y = p1;
  reinterpret_cast<uint2*>(a.dst8)[t] = q;
}

// ---------------------------------------------------------------------------
// k_pack10: all 10 weight matrices -> MFMA B-fragment order fp16.
// Fragment (kt,nt): lane l, reg j <- W[kt*32 + (l>>4)*8 + j][nt*16 + (l&15)]
// ---------------------------------------------------------------------------
struct PackArgs {
  const float* src[10];
  ushort_t* dst;
};

__global__ __launch_bounds__(256)
void k_pack10(PackArgs a) {
  const int b = blockIdx.x, tid = threadIdx.x;
  int job, tin;
  size_t doff;
  if (b < 112) {
    job = b >> 4; tin = ((b & 15) << 8) | tid;
    doff = (size_t)job * 32768;
  } else {
    job = 7 + ((b - 112) >> 3); tin = (((b - 112) & 7) << 8) | tid;
    doff = 7ull * 32768 + (size_t)(job - 7) * 16384;
  }
  const float* W = a.src[job];
  const int l = tin & 63;
  const int ktnt = tin >> 6;
  const int nt = ktnt & 7;
  const int kt = ktnt >> 3;
  const int col = nt * 16 + (l & 15);
  const int kb = kt * 32 + ((l >> 4) << 3);
  UH h[8];
#pragma unroll
  for (int j = 0; j < 8; ++j) h[j].h = __float2half_rn(W[(size_t)(kb + j) * DD + col]);
  uint4 o;
  o.x = (uint_t)h[0].s | ((uint_t)h[1].s << 16);
  o.y = (uint_t)h[2].s | ((uint_t)h[3].s << 16);
  o.z = (uint_t)h[4].s | ((uint_t)h[5].s << 16);
  o.w = (uint_t)h[6].s | ((uint_t)h[7].s << 16);
  *reinterpret_cast<uint4*>(a.dst + doff + (size_t)ktnt * 512 + l * 8) = o;
}

// ---------------------------------------------------------------------------
// k_mega: whole graph in one kernel. fp8 neighbor gathers (f16x2 accumulate,
// scalef32 unpack), fp16 self rows + MFMA path. launch_bounds(256,7): cap ~73
// regs; measured usage is ~40 (R9) so no spill (R7 lesson: f32 accs spilled).
// ---------------------------------------------------------------------------
struct MegaArgs {
  // items
  const int* item_idx; const ushort_t* item_t;
  const int* nbI[3]; const uchar_t* embI[3]; const ushort_t* pWI[3]; const float* bI[3];
  const ushort_t* pWsI; const float* bsI; const float* qI;
  ushort_t* hI; float* wsumI;
  // locs (g=0) / times (g=1)
  const int* sidx[2]; const ushort_t* st[2];
  const int* nbS[2][2]; const uchar_t* embS[2][2];
  const ushort_t* pWS[2][2]; const float* bS[2][2];
  const ushort_t* pWsS[2]; const float* bsS[2]; const float* qS[2];
  const float* session;
  ushort_t* hS[2]; float* wsumS[2];
};

__global__ __launch_bounds__(256, 7)
void k_mega(MegaArgs a) {
  __shared__ int ids[TRR];
  __shared__ int nidx[3][TRR][KK];
  __shared__ __align__(16) ushort_t xs[TRR][4 * DD + 8];   // 520: self|s1|s2|s3
  __shared__ float red[4][TRR];

  const int tid = threadIdx.x;
  const int l = tid & 63;
  const int w = tid >> 6;
  const int bid = blockIdx.x;

  const bool isS = bid < 128;
  const int g = isS ? (bid >> 6) : 0;
  const int bl = isS ? (bid & 63) : (bid - 128);
  const int n0 = bl * TRR;

  const int* sidx;
  const ushort_t* selft;
  const int* nb_[3];
  const uchar_t* emb_[3];
  const ushort_t* pW_[3];
  const float* bias_[3];
  const ushort_t* pws; const float* bss; const float* qp;
  ushort_t* hd; float* wbase;
  if (!isS) {
    sidx = a.item_idx; selft = a.item_t;
    nb_[0] = a.nbI[0]; nb_[1] = a.nbI[1]; nb_[2] = a.nbI[2];
    emb_[0] = a.embI[0]; emb_[1] = a.embI[1]; emb_[2] = a.embI[2];
    pW_[0] = a.pWI[0]; pW_[1] = a.pWI[1]; pW_[2] = a.pWI[2];
    bias_[0] = a.bI[0]; bias_[1] = a.bI[1]; bias_[2] = a.bI[2];
    pws = a.pWsI; bss = a.bsI; qp = a.qI;
    hd = a.hI; wbase = a.wsumI;
  } else if (g == 0) {
    sidx = a.sidx[0]; selft = a.st[0];
    nb_[0] = a.nbS[0][0]; nb_[1] = a.nbS[0][1]; nb_[2] = nullptr;
    emb_[0] = a.embS[0][0]; emb_[1] = a.embS[0][1]; emb_[2] = nullptr;
    pW_[0] = a.pWS[0][0]; pW_[1] = a.pWS[0][1]; pW_[2] = nullptr;
    bias_[0] = a.bS[0][0]; bias_[1] = a.bS[0][1]; bias_[2] = nullptr;
    pws = a.pWsS[0]; bss = a.bsS[0]; qp = a.qS[0];
    hd = a.hS[0]; wbase = a.wsumS[0];
  } else {
    sidx = a.sidx[1]; selft = a.st[1];
    nb_[0] = a.nbS[1][0]; nb_[1] = a.nbS[1][1]; nb_[2] = nullptr;
    emb_[0] = a.embS[1][0]; emb_[1] = a.embS[1][1]; emb_[2] = nullptr;
    pW_[0] = a.pWS[1][0]; pW_[1] = a.pWS[1][1]; pW_[2] = nullptr;
    bias_[0] = a.bS[1][0]; bias_[1] = a.bS[1][1]; bias_[2] = nullptr;
    pws = a.pWsS[1]; bss = a.bsS[1]; qp = a.qS[1];
    hd = a.hS[1]; wbase = a.wsumS[1];
  }

  if (tid < TRR) ids[tid] = sidx[n0 + tid];
  __syncthreads();

  const int gr = tid >> 4;        // row 0..15
  const int gsl = tid & 15;       // 8-elem slice within a row

  // stage neighbor index lists (edge-major)
#pragma unroll
  for (int e = 0; e < 3; ++e) {
    if (nb_[e]) {
      for (int t = tid; t < TRR * KK; t += 256) {
        const int rr = t / KK, kk = t - rr * KK;
        nidx[e][rr][kk] = nb_[e][(size_t)ids[rr] * KK + kk];
      }
    }
  }
  // self half of x (fp16 table)
  *reinterpret_cast<uint4*>(&xs[gr][gsl * 8]) =
      *reinterpret_cast<const uint4*>(selft + ((size_t)ids[gr] << 7) + gsl * 8);
  __syncthreads();

  // ---- concurrent fp8 gathers for all edges, f16x2 accumulation ----
  const _Float16 sch = (_Float16)(1.f / KK);
  const f16x2 scv = (f16x2){sch, sch};
  if (!isS) {
    UF A0, A1, A2;
#pragma unroll
    for (int i = 0; i < 4; ++i) {
      A0.v[i] = (f16x2)0; A1.v[i] = (f16x2)0; A2.v[i] = (f16x2)0;
    }
#pragma unroll
    for (int kb = 0; kb < KK; kb += 4) {
      uint2 u0[4], u1[4], u2[4];
#pragma unroll
      for (int j = 0; j < 4; ++j)
        u0[j] = *reinterpret_cast<const uint2*>(emb_[0] + ((size_t)nidx[0][gr][kb + j] << 7) + gsl * 8);
#pragma unroll
      for (int j = 0; j < 4; ++j)
        u1[j] = *reinterpret_cast<const uint2*>(emb_[1] + ((size_t)nidx[1][gr][kb + j] << 7) + gsl * 8);
#pragma unroll
      for (int j = 0; j < 4; ++j)
        u2[j] = *reinterpret_cast<const uint2*>(emb_[2] + ((size_t)nidx[2][gr][kb + j] << 7) + gsl * 8);
#pragma unroll
      for (int j = 0; j < 4; ++j) {
        f8acc(A0.v, u0[j]); f8acc(A1.v, u1[j]); f8acc(A2.v, u2[j]);
      }
    }
#pragma unroll
    for (int i = 0; i < 4; ++i) {
      A0.v[i] *= scv; A1.v[i] *= scv; A2.v[i] *= scv;
    }
    *reinterpret_cast<uint4*>(&xs[gr][1 * DD + gsl * 8]) = A0.u4;
    *reinterpret_cast<uint4*>(&xs[gr][2 * DD + gsl * 8]) = A1.u4;
    *reinterpret_cast<uint4*>(&xs[gr][3 * DD + gsl * 8]) = A2.u4;
  } else {
    UF A0, A1;
#pragma unroll
    for (int i = 0; i < 4; ++i) { A0.v[i] = (f16x2)0; A1.v[i] = (f16x2)0; }
#pragma unroll
    for (int kb = 0; kb < KK; kb += 5) {
      uint2 u0[5], u1[5];
#pragma unroll
      for (int j = 0; j < 5; ++j)
        u0[j] = *reinterpret_cast<const uint2*>(emb_[0] + ((size_t)nidx[0][gr][kb + j] << 7) + gsl * 8);
#pragma unroll
      for (int j = 0; j < 5; ++j)
        u1[j] = *reinterpret_cast<const uint2*>(emb_[1] + ((size_t)nidx[1][gr][kb + j] << 7) + gsl * 8);
#pragma unroll
      for (int j = 0; j < 5; ++j) { f8acc(A0.v, u0[j]); f8acc(A1.v, u1[j]); }
    }
#pragma unroll
    for (int i = 0; i < 4; ++i) { A0.v[i] *= scv; A1.v[i] *= scv; }
    *reinterpret_cast<uint4*>(&xs[gr][1 * DD + gsl * 8]) = A0.u4;
    *reinterpret_cast<uint4*>(&xs[gr][2 * DD + gsl * 8]) = A1.u4;
    // session -> slot 3 (fp16) + hbuf m=2
    const float* srow = a.session + (size_t)(n0 + gr) * DD + gsl * 8;
    const float4 v0 = *reinterpret_cast<const float4*>(srow);
    const float4 v1 = *reinterpret_cast<const float4*>(srow + 4);
    UH h0, h1, h2, h3, h4, h5, h6, h7;
    h0.h = __float2half_rn(v0.x); h1.h = __float2half_rn(v0.y);
    h2.h = __float2half_rn(v0.z); h3.h = __float2half_rn(v0.w);
    h4.h = __float2half_rn(v1.x); h5.h = __float2half_rn(v1.y);
    h6.h = __float2half_rn(v1.z); h7.h = __float2half_rn(v1.w);
    uint4 o;
    o.x = (uint_t)h0.s | ((uint_t)h1.s << 16);
    o.y = (uint_t)h2.s | ((uint_t)h3.s << 16);
    o.z = (uint_t)h4.s | ((uint_t)h5.s << 16);
    o.w = (uint_t)h6.s | ((uint_t)h7.s << 16);
    *reinterpret_cast<uint4*>(&xs[gr][3 * DD + gsl * 8]) = o;
    *reinterpret_cast<uint4*>(hd + (size_t)(n0 + gr) * 3 * DD + 2 * DD + gsl * 8) = o;
  }
  __syncthreads();

  // ---- per-edge MFMA + score ----
  const int nt0 = 2 * w;
  const int lcol = l & 15;
  const int g8 = (l >> 4) << 3;
  const int col0 = nt0 * 16 + lcol;
  const int col1 = col0 + 16;

#pragma unroll
  for (int e = 0; e < 3; ++e) {
    const bool full = (!isS) || (e < 2);
    if (full) {
      const ushort_t* pWp = pW_[e];
      const float* bp = bias_[e];
      f32x4 acc0, acc1;
      {
        const float b0 = bp[col0], b1 = bp[col1];
        acc0 = (f32x4){b0, b0, b0, b0};
        acc1 = (f32x4){b1, b1, b1, b1};
#pragma unroll
        for (int kt = 0; kt < 8; ++kt) {
          const int xcol = (kt < 4) ? (kt * 32 + g8) : (e * DD + kt * 32 + g8);
          const f16x8 A = *reinterpret_cast<const f16x8*>((const void*)&xs[lcol][xcol]);
          const f16x8 B0 = *reinterpret_cast<const f16x8*>(
              (const void*)(pWp + ((size_t)(kt * 8 + nt0) * 512) + l * 8));
          const f16x8 B1 = *reinterpret_cast<const f16x8*>(
              (const void*)(pWp + ((size_t)(kt * 8 + nt0 + 1) * 512) + l * 8));
          acc0 = __builtin_amdgcn_mfma_f32_16x16x32_f16(A, B0, acc0, 0, 0, 0);
          acc1 = __builtin_amdgcn_mfma_f32_16x16x32_f16(A, B1, acc1, 0, 0, 0);
        }
#pragma unroll
        for (int j = 0; j < 4; ++j) {
          acc0[j] = fmaxf(acc0[j], 0.f);
          acc1[j] = fmaxf(acc1[j], 0.f);
        }
      }
      __syncthreads();  // all A-reads of slot e+1 done before overwrite
      {
        const int rbase = (l >> 4) << 2;
#pragma unroll
        for (int j = 0; j < 4; ++j) {
          const int row = rbase + j;
          UH h0, h1;
          h0.h = __float2half_rn(acc0[j]);
          h1.h = __float2half_rn(acc1[j]);
          hd[(size_t)(n0 + row) * 3 * DD + e * DD + col0] = h0.s;
          hd[(size_t)(n0 + row) * 3 * DD + e * DD + col1] = h1.s;
          xs[row][(e + 1) * DD + col0] = h0.s;
          xs[row][(e + 1) * DD + col1] = h1.s;
        }
      }
      __syncthreads();  // h visible in LDS
    }
    // score: t = h @ Ws + bs; w = sum_cols tanh(t)*q
    {
      const float b0 = bss[col0], b1 = bss[col1];
      f32x4 s0 = (f32x4){b0, b0, b0, b0};
      f32x4 s1 = (f32x4){b1, b1, b1, b1};
#pragma unroll
      for (int kt = 0; kt < 4; ++kt) {
        const f16x8 A = *reinterpret_cast<const f16x8*>(
            (const void*)&xs[lcol][(e + 1) * DD + kt * 32 + g8]);
        const f16x8 B0 = *reinterpret_cast<const f16x8*>(
            (const void*)(pws + ((size_t)(kt * 8 + nt0) * 512) + l * 8));
        const f16x8 B1 = *reinterpret_cast<const f16x8*>(
            (const void*)(pws + ((size_t)(kt * 8 + nt0 + 1) * 512) + l * 8));
        s0 = __builtin_amdgcn_mfma_f32_16x16x32_f16(A, B0, s0, 0, 0, 0);
        s1 = __builtin_amdgcn_mfma_f32_16x16x32_f16(A, B1, s1, 0, 0, 0);
      }
      const float q0 = qp[col0], q1 = qp[col1];
      float p[4];
#pragma unroll
      for (int j = 0; j < 4; ++j)
        p[j] = fast_tanh(s0[j]) * q0 + fast_tanh(s1[j]) * q1;
#pragma unroll
      for (int off = 1; off < 16; off <<= 1) {
#pragma unroll
        for (int j = 0; j < 4; ++j) p[j] += __shfl_xor(p[j], off, 64);
      }
      if (lcol == 0) {
        const int rbase = (l >> 4) << 2;
#pragma unroll
        for (int j = 0; j < 4; ++j) red[w][rbase + j] = p[j];
      }
    }
    __syncthreads();
    if (tid < TRR) {
      float s = red[0][tid] + red[1][tid] + red[2][tid] + red[3][tid];
#pragma unroll
      for (int off = 1; off < 16; off <<= 1) s += __shfl_xor(s, off, 64);
      if (tid == 0) atomicAdd(&wbase[(bl & 63) * 4 + e], s);
    }
    __syncthreads();
  }
}

// ---------------------------------------------------------------------------
__global__ void k_beta(const float* __restrict__ wsum, float* __restrict__ beta) {
  if (threadIdx.x == 0 && blockIdx.x == 0) {
    const float invN[3] = {1.f / 51200.f, 1.f / 1024.f, 1.f / 1024.f};
    for (int g = 0; g < 3; ++g) {
      float s0 = 0.f, s1 = 0.f, s2 = 0.f;
      for (int bkt = 0; bkt < 64; ++bkt) {
        s0 += wsum[g * 256 + bkt * 4 + 0];
        s1 += wsum[g * 256 + bkt * 4 + 1];
        s2 += wsum[g * 256 + bkt * 4 + 2];
      }
      s0 *= invN[g]; s1 *= invN[g]; s2 *= invN[g];
      const float mx = fmaxf(s0, fmaxf(s1, s2));
      const float e0 = expf(s0 - mx), e1 = expf(s1 - mx), e2 = expf(s2 - mx);
      const float inv = 1.f / (e0 + e1 + e2);
      beta[g * 4 + 0] = e0 * inv;
      beta[g * 4 + 1] = e1 * inv;
      beta[g * 4 + 2] = e2 * inv;
    }
  }
}

__global__ void k_out(const ushort_t* __restrict__ h, const float* __restrict__ beta,
                      float* __restrict__ out) {
  const int idx = blockIdx.x * blockDim.x + threadIdx.x;
  const int row = idx >> 7;
  const int g = (row < 51200) ? 0 : ((row < 52224) ? 1 : 2);
  const float* bt = beta + g * 4;
  const size_t base = (size_t)idx + (size_t)row * 2 * DD;
  UH a, b, c;
  a.s = h[base]; b.s = h[base + DD]; c.s = h[base + 2 * DD];
  out[idx] = bt[0] * __half2float(a.h) + bt[1] * __half2float(b.h) +
             bt[2] * __half2float(c.h);
}

// ---------------------------------------------------------------------------

extern "C" void kernel_launch(void* const* d_in, const int* in_sizes, int n_in,
                              void* d_out, int out_size, void* d_ws, size_t ws_size,
                              hipStream_t stream) {
  const int*   item     = (const int*)  d_in[0];
  const int*   locs     = (const int*)  d_in[1];
  const int*   times    = (const int*)  d_in[2];
  const float* session  = (const float*)d_in[3];
  const float* loc_emb  = (const float*)d_in[4];
  const float* time_emb = (const float*)d_in[5];
  const float* item_emb = (const float*)d_in[6];
  const int* nb_IL = (const int*)d_in[7];
  const int* nb_TL = (const int*)d_in[8];
  const int* nb_IT = (const int*)d_in[9];
  const int* nb_LT = (const int*)d_in[10];
  const int* nb_II = (const int*)d_in[11];
  const int* nb_LI = (const int*)d_in[12];
  const int* nb_TI = (const int*)d_in[13];
  const float* W_IL = (const float*)d_in[14]; const float* b_IL = (const float*)d_in[15];
  const float* W_TL = (const float*)d_in[16]; const float* b_TL = (const float*)d_in[17];
  const float* W_IT = (const float*)d_in[18]; const float* b_IT = (const float*)d_in[19];
  const float* W_LT = (const float*)d_in[20]; const float* b_LT = (const float*)d_in[21];
  const float* W_II = (const float*)d_in[22]; const float* b_II = (const float*)d_in[23];
  const float* W_LI = (const float*)d_in[24]; const float* b_LI = (const float*)d_in[25];
  const float* W_TI = (const float*)d_in[26]; const float* b_TI = (const float*)d_in[27];
  const float* Ws_l = (const float*)d_in[28]; const float* bs_l = (const float*)d_in[29];
  const float* q_l  = (const float*)d_in[30];
  const float* Ws_t = (const float*)d_in[31]; const float* bs_t = (const float*)d_in[32];
  const float* q_t  = (const float*)d_in[33];
  const float* Ws_i = (const float*)d_in[34]; const float* bs_i = (const float*)d_in[35];
  const float* q_i  = (const float*)d_in[36];

  float* outp = (float*)d_out;

  // ws: wsum/beta(16K) | packed W(544K) | hbuf fp16(40.9M) | fp16 tables(28.7M)
  //     | fp8 tables(14.3M)  -- ~84.5MB total
  char* wsb = (char*)d_ws;
  float* wsum  = (float*)wsb;
  float* betap = (float*)wsb + 1024;
  ushort_t* pk = (ushort_t*)(wsb + 16384);
  ushort_t* pk_II = pk;
  ushort_t* pk_TI = pk_II + 32768;
  ushort_t* pk_LI = pk_TI + 32768;
  ushort_t* pk_IL = pk_LI + 32768;
  ushort_t* pk_TL = pk_IL + 32768;
  ushort_t* pk_IT = pk_TL + 32768;
  ushort_t* pk_LT = pk_IT + 32768;
  ushort_t* pk_Wi = pk_LT + 32768;
  ushort_t* pk_Wl = pk_Wi + 16384;
  ushort_t* pk_Wt = pk_Wl + 16384;
  ushort_t* hbuf  = pk_Wt + 16384;
  ushort_t* item_h = hbuf + (size_t)53248 * 3 * DD;
  ushort_t* loc_h  = item_h + (size_t)100000 * DD;
  ushort_t* time_h = loc_h + (size_t)10000 * DD;
  uchar_t* item_8 = (uchar_t*)(time_h + (size_t)2000 * DD);
  uchar_t* loc_8  = item_8 + (size_t)100000 * DD;
  uchar_t* time_8 = loc_8 + (size_t)10000 * DD;

  hipMemsetAsync(d_ws, 0, 16384, stream);

  CvtArgs ca;
  ca.item = item_emb; ca.loc = loc_emb; ca.timet = time_emb;
  ca.dst16 = item_h; ca.dst8 = item_8;
  k_cvt3<<<dim3(7000), dim3(256), 0, stream>>>(ca);

  PackArgs pa;
  pa.src[0] = W_II; pa.src[1] = W_TI; pa.src[2] = W_LI;
  pa.src[3] = W_IL; pa.src[4] = W_TL; pa.src[5] = W_IT; pa.src[6] = W_LT;
  pa.src[7] = Ws_i; pa.src[8] = Ws_l; pa.src[9] = Ws_t;
  pa.dst = pk;
  k_pack10<<<dim3(136), dim3(256), 0, stream>>>(pa);

  ushort_t* h_items = hbuf;
  ushort_t* h_locs  = hbuf + (size_t)51200 * 3 * DD;
  ushort_t* h_times = hbuf + (size_t)52224 * 3 * DD;

  MegaArgs ma;
  ma.item_idx = item; ma.item_t = item_h;
  ma.nbI[0] = nb_II; ma.nbI[1] = nb_TI; ma.nbI[2] = nb_LI;
  ma.embI[0] = item_8; ma.embI[1] = time_8; ma.embI[2] = loc_8;
  ma.pWI[0] = pk_II; ma.pWI[1] = pk_TI; ma.pWI[2] = pk_LI;
  ma.bI[0] = b_II; ma.bI[1] = b_TI; ma.bI[2] = b_LI;
  ma.pWsI = pk_Wi; ma.bsI = bs_i; ma.qI = q_i;
  ma.hI = h_items; ma.wsumI = wsum + 0;
  ma.sidx[0] = locs;  ma.sidx[1] = times;
  ma.st[0] = loc_h;   ma.st[1] = time_h;
  ma.nbS[0][0] = nb_IL; ma.nbS[0][1] = nb_TL;
  ma.nbS[1][0] = nb_IT; ma.nbS[1][1] = nb_LT;
  ma.embS[0][0] = item_8; ma.embS[0][1] = time_8;
  ma.embS[1][0] = item_8; ma.embS[1][1] = loc_8;
  ma.pWS[0][0] = pk_IL; ma.pWS[0][1] = pk_TL;
  ma.pWS[1][0] = pk_IT; ma.pWS[1][1] = pk_LT;
  ma.bS[0][0] = b_IL; ma.bS[0][1] = b_TL;
  ma.bS[1][0] = b_IT; ma.bS[1][1] = b_LT;
  ma.pWsS[0] = pk_Wl; ma.pWsS[1] = pk_Wt;
  ma.bsS[0] = bs_l; ma.bsS[1] = bs_t;
  ma.qS[0] = q_l; ma.qS[1] = q_t;
  ma.session = session;
  ma.hS[0] = h_locs; ma.hS[1] = h_times;
  ma.wsumS[0] = wsum + 256; ma.wsumS[1] = wsum + 512;
  k_mega<<<dim3(128 + 51200 / TRR), dim3(256), 0, stream>>>(ma);

  k_beta<<<dim3(1), dim3(64), 0, stream>>>(wsum, betap);
  k_out<<<dim3((53248 * 128) / 256), dim3(256), 0, stream>>>(hbuf, betap, outp);
}

// Round 11
// 123.010 us; speedup vs baseline: 5.1244x; 1.0044x over previous
//
#include <hip/hip_runtime.h>
#include <hip/hip_fp16.h>

#define DD 128
#define KK 20
#define TRR 32
#define NT 512

typedef unsigned int uint_t;
typedef unsigned short ushort_t;
typedef unsigned char uchar_t;
typedef _Float16 f16x8 __attribute__((ext_vector_type(8)));
typedef _Float16 f16x2 __attribute__((ext_vector_type(2)));
typedef float f32x4 __attribute__((ext_vector_type(4)));
typedef float f32x2 __attribute__((ext_vector_type(2)));

union UH { __half h; ushort_t s; };
union UF { f16x2 v[4]; uint4 u4; };

#if __has_builtin(__builtin_amdgcn_cvt_scalef32_pk_f16_fp8)
#define HAVE_SCALEF32 1
#endif

__device__ __forceinline__ float fast_tanh(float x) {
  const float e = __expf(2.f * x);
  return 1.f - 2.f / (e + 1.f);
}

// unpack 8 fp8 (uint2) -> accumulate into 4 packed f16x2
__device__ __forceinline__ void f8acc(f16x2* a, const uint2 v) {
#ifdef HAVE_SCALEF32
  a[0] += __builtin_amdgcn_cvt_scalef32_pk_f16_fp8(v.x, 1.0f, false);
  a[1] += __builtin_amdgcn_cvt_scalef32_pk_f16_fp8(v.x, 1.0f, true);
  a[2] += __builtin_amdgcn_cvt_scalef32_pk_f16_fp8(v.y, 1.0f, false);
  a[3] += __builtin_amdgcn_cvt_scalef32_pk_f16_fp8(v.y, 1.0f, true);
#else
  f32x2 p;
  p = __builtin_amdgcn_cvt_pk_f32_fp8(v.x, false);
  a[0] += __builtin_amdgcn_cvt_pkrtz(p[0], p[1]);
  p = __builtin_amdgcn_cvt_pk_f32_fp8(v.x, true);
  a[1] += __builtin_amdgcn_cvt_pkrtz(p[0], p[1]);
  p = __builtin_amdgcn_cvt_pk_f32_fp8(v.y, false);
  a[2] += __builtin_amdgcn_cvt_pkrtz(p[0], p[1]);
  p = __builtin_amdgcn_cvt_pk_f32_fp8(v.y, true);
  a[3] += __builtin_amdgcn_cvt_pkrtz(p[0], p[1]);
#endif
}

// ---------------------------------------------------------------------------
// k_cvt3: three f32 tables -> fp16 region (self reads) + fp8 region (gathers)
// ---------------------------------------------------------------------------
struct CvtArgs {
  const float* item; const float* loc; const float* timet;
  ushort_t* dst16; uchar_t* dst8;
};

__global__ __launch_bounds__(256)
void k_cvt3(CvtArgs a) {
  const int t = blockIdx.x * blockDim.x + threadIdx.x;  // 7000*256 = 1,792,000
  const float* src;
  if (t < 1600000) src = a.item + (size_t)t * 8;
  else if (t < 1760000) src = a.loc + ((size_t)t - 1600000) * 8;
  else src = a.timet + ((size_t)t - 1760000) * 8;
  const float4* ip = reinterpret_cast<const float4*>(src);
  const float4 x = ip[0], y = ip[1];
  UH h[8];
  h[0].h = __float2half_rn(x.x); h[1].h = __float2half_rn(x.y);
  h[2].h = __float2half_rn(x.z); h[3].h = __float2half_rn(x.w);
  h[4].h = __float2half_rn(y.x); h[5].h = __float2half_rn(y.y);
  h[6].h = __float2half_rn(y.z); h[7].h = __float2half_rn(y.w);
  uint4 o;
  o.x = (uint_t)h[0].s | ((uint_t)h[1].s << 16);
  o.y = (uint_t)h[2].s | ((uint_t)h[3].s << 16);
  o.z = (uint_t)h[4].s | ((uint_t)h[5].s << 16);
  o.w = (uint_t)h[6].s | ((uint_t)h[7].s << 16);
  reinterpret_cast<uint4*>(a.dst16)[t] = o;
  uint_t p0 = __builtin_amdgcn_cvt_pk_fp8_f32(x.x, x.y, 0u, false);
  p0 = __builtin_amdgcn_cvt_pk_fp8_f32(x.z, x.w, p0, true);
  uint_t p1 = __builtin_amdgcn_cvt_pk_fp8_f32(y.x, y.y, 0u, false);
  p1 = __builtin_amdgcn_cvt_pk_fp8_f32(y.z, y.w, p1, true);
  uint2 q; q.x = p0; q.y = p1;
  reinterpret_cast<uint2*>(a.dst8)[t] = q;
}

// ---------------------------------------------------------------------------
// k_pack10: all 10 weight matrices -> MFMA B-fragment order fp16.
// Fragment (kt,nt): lane l, reg j <- W[kt*32 + (l>>4)*8 + j][nt*16 + (l&15)]
// ---------------------------------------------------------------------------
struct PackArgs {
  const float* src[10];
  ushort_t* dst;
};

__global__ __launch_bounds__(256)
void k_pack10(PackArgs a) {
  const int b = blockIdx.x, tid = threadIdx.x;
  int job, tin;
  size_t doff;
  if (b < 112) {
    job = b >> 4; tin = ((b & 15) << 8) | tid;
    doff = (size_t)job * 32768;
  } else {
    job = 7 + ((b - 112) >> 3); tin = (((b - 112) & 7) << 8) | tid;
    doff = 7ull * 32768 + (size_t)(job - 7) * 16384;
  }
  const float* W = a.src[job];
  const int l = tin & 63;
  const int ktnt = tin >> 6;
  const int nt = ktnt & 7;
  const int kt = ktnt >> 3;
  const int col = nt * 16 + (l & 15);
  const int kb = kt * 32 + ((l >> 4) << 3);
  UH h[8];
#pragma unroll
  for (int j = 0; j < 8; ++j) h[j].h = __float2half_rn(W[(size_t)(kb + j) * DD + col]);
  uint4 o;
  o.x = (uint_t)h[0].s | ((uint_t)h[1].s << 16);
  o.y = (uint_t)h[2].s | ((uint_t)h[3].s << 16);
  o.z = (uint_t)h[4].s | ((uint_t)h[5].s << 16);
  o.w = (uint_t)h[6].s | ((uint_t)h[7].s << 16);
  *reinterpret_cast<uint4*>(a.dst + doff + (size_t)ktnt * 512 + l * 8) = o;
}

// ---------------------------------------------------------------------------
// k_mega: whole graph, 512 threads = 8 waves, 32 rows/block.
//  Wave w owns ntile w (cols w*16..w*16+15); two 16-row groups share the
//  B-fragments (halves packed-W L2 traffic vs the 16-row version).
//  blocks 0..63: locs/times (32 blocks each); 64..: items (1600 blocks).
// ---------------------------------------------------------------------------
struct MegaArgs {
  // items
  const int* item_idx; const ushort_t* item_t;
  const int* nbI[3]; const uchar_t* embI[3]; const ushort_t* pWI[3]; const float* bI[3];
  const ushort_t* pWsI; const float* bsI; const float* qI;
  ushort_t* hI; float* wsumI;
  // locs (g=0) / times (g=1)
  const int* sidx[2]; const ushort_t* st[2];
  const int* nbS[2][2]; const uchar_t* embS[2][2];
  const ushort_t* pWS[2][2]; const float* bS[2][2];
  const ushort_t* pWsS[2]; const float* bsS[2]; const float* qS[2];
  const float* session;
  ushort_t* hS[2]; float* wsumS[2];
};

__global__ __launch_bounds__(NT, 6)
void k_mega(MegaArgs a) {
  __shared__ int ids[TRR];
  __shared__ int nidx[3][TRR][KK];
  __shared__ __align__(16) ushort_t xs[TRR][4 * DD + 8];   // 520: self|s1|s2|s3
  __shared__ float red[8][TRR];

  const int tid = threadIdx.x;
  const int l = tid & 63;
  const int w = tid >> 6;         // wave 0..7 -> ntile
  const int bid = blockIdx.x;

  const bool isS = bid < 64;
  const int g = isS ? (bid >> 5) : 0;
  const int bl = isS ? (bid & 31) : (bid - 64);
  const int n0 = bl * TRR;

  const int* sidx;
  const ushort_t* selft;
  const int* nb_[3];
  const uchar_t* emb_[3];
  const ushort_t* pW_[3];
  const float* bias_[3];
  const ushort_t* pws; const float* bss; const float* qp;
  ushort_t* hd; float* wbase;
  if (!isS) {
    sidx = a.item_idx; selft = a.item_t;
    nb_[0] = a.nbI[0]; nb_[1] = a.nbI[1]; nb_[2] = a.nbI[2];
    emb_[0] = a.embI[0]; emb_[1] = a.embI[1]; emb_[2] = a.embI[2];
    pW_[0] = a.pWI[0]; pW_[1] = a.pWI[1]; pW_[2] = a.pWI[2];
    bias_[0] = a.bI[0]; bias_[1] = a.bI[1]; bias_[2] = a.bI[2];
    pws = a.pWsI; bss = a.bsI; qp = a.qI;
    hd = a.hI; wbase = a.wsumI;
  } else if (g == 0) {
    sidx = a.sidx[0]; selft = a.st[0];
    nb_[0] = a.nbS[0][0]; nb_[1] = a.nbS[0][1]; nb_[2] = nullptr;
    emb_[0] = a.embS[0][0]; emb_[1] = a.embS[0][1]; emb_[2] = nullptr;
    pW_[0] = a.pWS[0][0]; pW_[1] = a.pWS[0][1]; pW_[2] = nullptr;
    bias_[0] = a.bS[0][0]; bias_[1] = a.bS[0][1]; bias_[2] = nullptr;
    pws = a.pWsS[0]; bss = a.bsS[0]; qp = a.qS[0];
    hd = a.hS[0]; wbase = a.wsumS[0];
  } else {
    sidx = a.sidx[1]; selft = a.st[1];
    nb_[0] = a.nbS[1][0]; nb_[1] = a.nbS[1][1]; nb_[2] = nullptr;
    emb_[0] = a.embS[1][0]; emb_[1] = a.embS[1][1]; emb_[2] = nullptr;
    pW_[0] = a.pWS[1][0]; pW_[1] = a.pWS[1][1]; pW_[2] = nullptr;
    bias_[0] = a.bS[1][0]; bias_[1] = a.bS[1][1]; bias_[2] = nullptr;
    pws = a.pWsS[1]; bss = a.bsS[1]; qp = a.qS[1];
    hd = a.hS[1]; wbase = a.wsumS[1];
  }

  if (tid < TRR) ids[tid] = sidx[n0 + tid];
  __syncthreads();

  const int gr = tid >> 4;        // row 0..31 (one row per thread)
  const int gsl = tid & 15;       // 8-elem slice within a row

  // stage neighbor index lists (edge-major)
#pragma unroll
  for (int e = 0; e < 3; ++e) {
    if (nb_[e]) {
      for (int t = tid; t < TRR * KK; t += NT) {
        const int rr = t / KK, kk = t - rr * KK;
        nidx[e][rr][kk] = nb_[e][(size_t)ids[rr] * KK + kk];
      }
    }
  }
  // self half of x (fp16 table)
  *reinterpret_cast<uint4*>(&xs[gr][gsl * 8]) =
      *reinterpret_cast<const uint4*>(selft + ((size_t)ids[gr] << 7) + gsl * 8);
  __syncthreads();

  // ---- concurrent fp8 gathers for all edges, f16x2 accumulation ----
  const _Float16 sch = (_Float16)(1.f / KK);
  const f16x2 scv = (f16x2){sch, sch};
  if (!isS) {
    UF A0, A1, A2;
#pragma unroll
    for (int i = 0; i < 4; ++i) {
      A0.v[i] = (f16x2)0; A1.v[i] = (f16x2)0; A2.v[i] = (f16x2)0;
    }
#pragma unroll
    for (int kb = 0; kb < KK; kb += 4) {
      uint2 u0[4], u1[4], u2[4];
#pragma unroll
      for (int j = 0; j < 4; ++j)
        u0[j] = *reinterpret_cast<const uint2*>(emb_[0] + ((size_t)nidx[0][gr][kb + j] << 7) + gsl * 8);
#pragma unroll
      for (int j = 0; j < 4; ++j)
        u1[j] = *reinterpret_cast<const uint2*>(emb_[1] + ((size_t)nidx[1][gr][kb + j] << 7) + gsl * 8);
#pragma unroll
      for (int j = 0; j < 4; ++j)
        u2[j] = *reinterpret_cast<const uint2*>(emb_[2] + ((size_t)nidx[2][gr][kb + j] << 7) + gsl * 8);
#pragma unroll
      for (int j = 0; j < 4; ++j) {
        f8acc(A0.v, u0[j]); f8acc(A1.v, u1[j]); f8acc(A2.v, u2[j]);
      }
    }
#pragma unroll
    for (int i = 0; i < 4; ++i) {
      A0.v[i] *= scv; A1.v[i] *= scv; A2.v[i] *= scv;
    }
    *reinterpret_cast<uint4*>(&xs[gr][1 * DD + gsl * 8]) = A0.u4;
    *reinterpret_cast<uint4*>(&xs[gr][2 * DD + gsl * 8]) = A1.u4;
    *reinterpret_cast<uint4*>(&xs[gr][3 * DD + gsl * 8]) = A2.u4;
  } else {
    UF A0, A1;
#pragma unroll
    for (int i = 0; i < 4; ++i) { A0.v[i] = (f16x2)0; A1.v[i] = (f16x2)0; }
#pragma unroll
    for (int kb = 0; kb < KK; kb += 5) {
      uint2 u0[5], u1[5];
#pragma unroll
      for (int j = 0; j < 5; ++j)
        u0[j] = *reinterpret_cast<const uint2*>(emb_[0] + ((size_t)nidx[0][gr][kb + j] << 7) + gsl * 8);
#pragma unroll
      for (int j = 0; j < 5; ++j)
        u1[j] = *reinterpret_cast<const uint2*>(emb_[1] + ((size_t)nidx[1][gr][kb + j] << 7) + gsl * 8);
#pragma unroll
      for (int j = 0; j < 5; ++j) { f8acc(A0.v, u0[j]); f8acc(A1.v, u1[j]); }
    }
#pragma unroll
    for (int i = 0; i < 4; ++i) { A0.v[i] *= scv; A1.v[i] *= scv; }
    *reinterpret_cast<uint4*>(&xs[gr][1 * DD + gsl * 8]) = A0.u4;
    *reinterpret_cast<uint4*>(&xs[gr][2 * DD + gsl * 8]) = A1.u4;
    // session -> slot 3 (fp16) + hbuf m=2
    const float* srow = a.session + (size_t)(n0 + gr) * DD + gsl * 8;
    const float4 v0 = *reinterpret_cast<const float4*>(srow);
    const float4 v1 = *reinterpret_cast<const float4*>(srow + 4);
    UH h0, h1, h2, h3, h4, h5, h6, h7;
    h0.h = __float2half_rn(v0.x); h1.h = __float2half_rn(v0.y);
    h2.h = __float2half_rn(v0.z); h3.h = __float2half_rn(v0.w);
    h4.h = __float2half_rn(v1.x); h5.h = __float2half_rn(v1.y);
    h6.h = __float2half_rn(v1.z); h7.h = __float2half_rn(v1.w);
    uint4 o;
    o.x = (uint_t)h0.s | ((uint_t)h1.s << 16);
    o.y = (uint_t)h2.s | ((uint_t)h3.s << 16);
    o.z = (uint_t)h4.s | ((uint_t)h5.s << 16);
    o.w = (uint_t)h6.s | ((uint_t)h7.s << 16);
    *reinterpret_cast<uint4*>(&xs[gr][3 * DD + gsl * 8]) = o;
    *reinterpret_cast<uint4*>(hd + (size_t)(n0 + gr) * 3 * DD + 2 * DD + gsl * 8) = o;
  }
  __syncthreads();

  // ---- per-edge MFMA + score. wave w -> ntile w; 2 row-groups share B ----
  const int lcol = l & 15;
  const int g8 = (l >> 4) << 3;
  const int col0 = w * 16 + lcol;

#pragma unroll
  for (int e = 0; e < 3; ++e) {
    const bool full = (!isS) || (e < 2);
    if (full) {
      const ushort_t* pWp = pW_[e];
      const float* bp = bias_[e];
      f32x4 acc0, acc1;   // rows 0-15 / rows 16-31
      {
        const float b0 = bp[col0];
        acc0 = (f32x4){b0, b0, b0, b0};
        acc1 = acc0;
#pragma unroll
        for (int kt = 0; kt < 8; ++kt) {
          const int xcol = (kt < 4) ? (kt * 32 + g8) : (e * DD + kt * 32 + g8);
          const f16x8 Aa = *reinterpret_cast<const f16x8*>((const void*)&xs[lcol][xcol]);
          const f16x8 Ab = *reinterpret_cast<const f16x8*>((const void*)&xs[16 + lcol][xcol]);
          const f16x8 B = *reinterpret_cast<const f16x8*>(
              (const void*)(pWp + ((size_t)(kt * 8 + w) * 512) + l * 8));
          acc0 = __builtin_amdgcn_mfma_f32_16x16x32_f16(Aa, B, acc0, 0, 0, 0);
          acc1 = __builtin_amdgcn_mfma_f32_16x16x32_f16(Ab, B, acc1, 0, 0, 0);
        }
#pragma unroll
        for (int j = 0; j < 4; ++j) {
          acc0[j] = fmaxf(acc0[j], 0.f);
          acc1[j] = fmaxf(acc1[j], 0.f);
        }
      }
      __syncthreads();  // all A-reads of slot e+1 done before overwrite
      {
        const int rbase = (l >> 4) << 2;
#pragma unroll
        for (int j = 0; j < 4; ++j) {
          const int r0 = rbase + j, r1 = 16 + rbase + j;
          UH h0, h1;
          h0.h = __float2half_rn(acc0[j]);
          h1.h = __float2half_rn(acc1[j]);
          hd[(size_t)(n0 + r0) * 3 * DD + e * DD + col0] = h0.s;
          hd[(size_t)(n0 + r1) * 3 * DD + e * DD + col0] = h1.s;
          xs[r0][(e + 1) * DD + col0] = h0.s;
          xs[r1][(e + 1) * DD + col0] = h1.s;
        }
      }
      __syncthreads();  // h visible in LDS
    }
    // score: t = h @ Ws + bs; w-score = sum_cols tanh(t)*q
    {
      const float b0 = bss[col0];
      f32x4 s0 = (f32x4){b0, b0, b0, b0};
      f32x4 s1 = s0;
#pragma unroll
      for (int kt = 0; kt < 4; ++kt) {
        const f16x8 Aa = *reinterpret_cast<const f16x8*>(
            (const void*)&xs[lcol][(e + 1) * DD + kt * 32 + g8]);
        const f16x8 Ab = *reinterpret_cast<const f16x8*>(
            (const void*)&xs[16 + lcol][(e + 1) * DD + kt * 32 + g8]);
        const f16x8 B = *reinterpret_cast<const f16x8*>(
            (const void*)(pws + ((size_t)(kt * 8 + w) * 512) + l * 8));
        s0 = __builtin_amdgcn_mfma_f32_16x16x32_f16(Aa, B, s0, 0, 0, 0);
        s1 = __builtin_amdgcn_mfma_f32_16x16x32_f16(Ab, B, s1, 0, 0, 0);
      }
      const float q0 = qp[col0];
      float p0[4], p1[4];
#pragma unroll
      for (int j = 0; j < 4; ++j) {
        p0[j] = fast_tanh(s0[j]) * q0;
        p1[j] = fast_tanh(s1[j]) * q0;
      }
#pragma unroll
      for (int off = 1; off < 16; off <<= 1) {
#pragma unroll
        for (int j = 0; j < 4; ++j) {
          p0[j] += __shfl_xor(p0[j], off, 64);
          p1[j] += __shfl_xor(p1[j], off, 64);
        }
      }
      if (lcol == 0) {
        const int rbase = (l >> 4) << 2;
#pragma unroll
        for (int j = 0; j < 4; ++j) {
          red[w][rbase + j] = p0[j];
          red[w][16 + rbase + j] = p1[j];
        }
      }
    }
    __syncthreads();
    if (tid < TRR) {
      float s = 0.f;
#pragma unroll
      for (int ww = 0; ww < 8; ++ww) s += red[ww][tid];
#pragma unroll
      for (int off = 1; off < 32; off <<= 1) s += __shfl_xor(s, off, 64);
      if (tid == 0) atomicAdd(&wbase[(bl & 63) * 4 + e], s);
    }
    __syncthreads();
  }
}

// ---------------------------------------------------------------------------
__global__ void k_beta(const float* __restrict__ wsum, float* __restrict__ beta) {
  if (threadIdx.x == 0 && blockIdx.x == 0) {
    const float invN[3] = {1.f / 51200.f, 1.f / 1024.f, 1.f / 1024.f};
    for (int g = 0; g < 3; ++g) {
      float s0 = 0.f, s1 = 0.f, s2 = 0.f;
      for (int bkt = 0; bkt < 64; ++bkt) {
        s0 += wsum[g * 256 + bkt * 4 + 0];
        s1 += wsum[g * 256 + bkt * 4 + 1];
        s2 += wsum[g * 256 + bkt * 4 + 2];
      }
      s0 *= invN[g]; s1 *= invN[g]; s2 *= invN[g];
      const float mx = fmaxf(s0, fmaxf(s1, s2));
      const float e0 = expf(s0 - mx), e1 = expf(s1 - mx), e2 = expf(s2 - mx);
      const float inv = 1.f / (e0 + e1 + e2);
      beta[g * 4 + 0] = e0 * inv;
      beta[g * 4 + 1] = e1 * inv;
      beta[g * 4 + 2] = e2 * inv;
    }
  }
}

__global__ void k_out(const ushort_t* __restrict__ h, const float* __restrict__ beta,
                      float* __restrict__ out) {
  const int idx = blockIdx.x * blockDim.x + threadIdx.x;
  const int row = idx >> 7;
  const int g = (row < 51200) ? 0 : ((row < 52224) ? 1 : 2);
  const float* bt = beta + g * 4;
  const size_t base = (size_t)idx + (size_t)row * 2 * DD;
  UH a, b, c;
  a.s = h[base]; b.s = h[base + DD]; c.s = h[base + 2 * DD];
  out[idx] = bt[0] * __half2float(a.h) + bt[1] * __half2float(b.h) +
             bt[2] * __half2float(c.h);
}

// ---------------------------------------------------------------------------

extern "C" void kernel_launch(void* const* d_in, const int* in_sizes, int n_in,
                              void* d_out, int out_size, void* d_ws, size_t ws_size,
                              hipStream_t stream) {
  const int*   item     = (const int*)  d_in[0];
  const int*   locs     = (const int*)  d_in[1];
  const int*   times    = (const int*)  d_in[2];
  const float* session  = (const float*)d_in[3];
  const float* loc_emb  = (const float*)d_in[4];
  const float* time_emb = (const float*)d_in[5];
  const float* item_emb = (const float*)d_in[6];
  const int* nb_IL = (const int*)d_in[7];
  const int* nb_TL = (const int*)d_in[8];
  const int* nb_IT = (const int*)d_in[9];
  const int* nb_LT = (const int*)d_in[10];
  const int* nb_II = (const int*)d_in[11];
  const int* nb_LI = (const int*)d_in[12];
  const int* nb_TI = (const int*)d_in[13];
  const float* W_IL = (const float*)d_in[14]; const float* b_IL = (const float*)d_in[15];
  const float* W_TL = (const float*)d_in[16]; const float* b_TL = (const float*)d_in[17];
  const float* W_IT = (const float*)d_in[18]; const float* b_IT = (const float*)d_in[19];
  const float* W_LT = (const float*)d_in[20]; const float* b_LT = (const float*)d_in[21];
  const float* W_II = (const float*)d_in[22]; const float* b_II = (const float*)d_in[23];
  const float* W_LI = (const float*)d_in[24]; const float* b_LI = (const float*)d_in[25];
  const float* W_TI = (const float*)d_in[26]; const float* b_TI = (const float*)d_in[27];
  const float* Ws_l = (const float*)d_in[28]; const float* bs_l = (const float*)d_in[29];
  const float* q_l  = (const float*)d_in[30];
  const float* Ws_t = (const float*)d_in[31]; const float* bs_t = (const float*)d_in[32];
  const float* q_t  = (const float*)d_in[33];
  const float* Ws_i = (const float*)d_in[34]; const float* bs_i = (const float*)d_in[35];
  const float* q_i  = (const float*)d_in[36];

  float* outp = (float*)d_out;

  // ws: wsum/beta(16K) | packed W(544K) | hbuf fp16(40.9M) | fp16 tables(28.7M)
  //     | fp8 tables(14.3M)  -- ~84.5MB total
  char* wsb = (char*)d_ws;
  float* wsum  = (float*)wsb;
  float* betap = (float*)wsb + 1024;
  ushort_t* pk = (ushort_t*)(wsb + 16384);
  ushort_t* pk_II = pk;
  ushort_t* pk_TI = pk_II + 32768;
  ushort_t* pk_LI = pk_TI + 32768;
  ushort_t* pk_IL = pk_LI + 32768;
  ushort_t* pk_TL = pk_IL + 32768;
  ushort_t* pk_IT = pk_TL + 32768;
  ushort_t* pk_LT = pk_IT + 32768;
  ushort_t* pk_Wi = pk_LT + 32768;
  ushort_t* pk_Wl = pk_Wi + 16384;
  ushort_t* pk_Wt = pk_Wl + 16384;
  ushort_t* hbuf  = pk_Wt + 16384;
  ushort_t* item_h = hbuf + (size_t)53248 * 3 * DD;
  ushort_t* loc_h  = item_h + (size_t)100000 * DD;
  ushort_t* time_h = loc_h + (size_t)10000 * DD;
  uchar_t* item_8 = (uchar_t*)(time_h + (size_t)2000 * DD);
  uchar_t* loc_8  = item_8 + (size_t)100000 * DD;
  uchar_t* time_8 = loc_8 + (size_t)10000 * DD;

  hipMemsetAsync(d_ws, 0, 16384, stream);

  CvtArgs ca;
  ca.item = item_emb; ca.loc = loc_emb; ca.timet = time_emb;
  ca.dst16 = item_h; ca.dst8 = item_8;
  k_cvt3<<<dim3(7000), dim3(256), 0, stream>>>(ca);

  PackArgs pa;
  pa.src[0] = W_II; pa.src[1] = W_TI; pa.src[2] = W_LI;
  pa.src[3] = W_IL; pa.src[4] = W_TL; pa.src[5] = W_IT; pa.src[6] = W_LT;
  pa.src[7] = Ws_i; pa.src[8] = Ws_l; pa.src[9] = Ws_t;
  pa.dst = pk;
  k_pack10<<<dim3(136), dim3(256), 0, stream>>>(pa);

  ushort_t* h_items = hbuf;
  ushort_t* h_locs  = hbuf + (size_t)51200 * 3 * DD;
  ushort_t* h_times = hbuf + (size_t)52224 * 3 * DD;

  MegaArgs ma;
  ma.item_idx = item; ma.item_t = item_h;
  ma.nbI[0] = nb_II; ma.nbI[1] = nb_TI; ma.nbI[2] = nb_LI;
  ma.embI[0] = item_8; ma.embI[1] = time_8; ma.embI[2] = loc_8;
  ma.pWI[0] = pk_II; ma.pWI[1] = pk_TI; ma.pWI[2] = pk_LI;
  ma.bI[0] = b_II; ma.bI[1] = b_TI; ma.bI[2] = b_LI;
  ma.pWsI = pk_Wi; ma.bsI = bs_i; ma.qI = q_i;
  ma.hI = h_items; ma.wsumI = wsum + 0;
  ma.sidx[0] = locs;  ma.sidx[1] = times;
  ma.st[0] = loc_h;   ma.st[1] = time_h;
  ma.nbS[0][0] = nb_IL; ma.nbS[0][1] = nb_TL;
  ma.nbS[1][0] = nb_IT; ma.nbS[1][1] = nb_LT;
  ma.embS[0][0] = item_8; ma.embS[0][1] = time_8;
  ma.embS[1][0] = item_8; ma.embS[1][1] = loc_8;
  ma.pWS[0][0] = pk_IL; ma.pWS[0][1] = pk_TL;
  ma.pWS[1][0] = pk_IT; ma.pWS[1][1] = pk_LT;
  ma.bS[0][0] = b_IL; ma.bS[0][1] = b_TL;
  ma.bS[1][0] = b_IT; ma.bS[1][1] = b_LT;
  ma.pWsS[0] = pk_Wl; ma.pWsS[1] = pk_Wt;
  ma.bsS[0] = bs_l; ma.bsS[1] = bs_t;
  ma.qS[0] = q_l; ma.qS[1] = q_t;
  ma.session = session;
  ma.hS[0] = h_locs; ma.hS[1] = h_times;
  ma.wsumS[0] = wsum + 256; ma.wsumS[1] = wsum + 512;
  k_mega<<<dim3(64 + 51200 / TRR), dim3(NT), 0, stream>>>(ma);

  k_beta<<<dim3(1), dim3(64), 0, stream>>>(wsum, betap);
  k_out<<<dim3((53248 * 128) / 256), dim3(256), 0, stream>>>(hbuf, betap, outp);
}